// Round 14
// baseline (1772.825 us; speedup 1.0000x reference)
//
#include <hip/hip_runtime.h>
#include <math.h>

typedef __attribute__((ext_vector_type(4))) float f32x4;
typedef __attribute__((ext_vector_type(8))) short short8;
typedef __attribute__((ext_vector_type(4))) unsigned int u32x4;
typedef unsigned short ushort_t;
typedef unsigned int uint_t;

// ---------------- workspace layout (float offsets), lifetime-packed, PADDED activations ----
static const size_t A_OFF      = 0;
static const size_t C_OFF      = 0;
static const size_t D_OFF      = 9469952;
static const size_t E_OFF      = 18939904;
static const size_t Q_OFF      = 21037056;
static const size_t B_OFF      = 34611200;
static const size_t CBT_OFF    = 52453376;  // 64*1024
static const size_t CNORM_OFF  = 52518912;  // 1024
static const size_t COUNTS_OFF = 52519936;  // 1024
static const size_t SUMSQ_OFF  = 52520960;  // 1 (+3)
static const size_t WT_OFF     = 52520964;  // transposed weights + bf16/split weights

__device__ __forceinline__ ushort_t f2b(float f) {
  uint_t u = __float_as_uint(f);
  uint_t r = (u + 0x7FFFu + ((u >> 16) & 1u)) >> 16;
  return (ushort_t)r;
}
__device__ __forceinline__ float b2f(ushort_t h) {
  return __uint_as_float(((uint_t)h) << 16);
}

// ---------------- utility: zero pad ring of one padded plane ----------------
__global__ void k_halo(float* __restrict__ buf, int HP, int WP) {
  const int plane = blockIdx.x;
  float* p = buf + (size_t)plane * HP * WP;
  const int ring = 2 * (HP + WP) - 4;
  for (int i = threadIdx.x; i < ring; i += blockDim.x) {
    int idx;
    if (i < WP) idx = i;
    else if (i < 2 * WP) idx = (HP - 1) * WP + (i - WP);
    else {
      const int j = i - 2 * WP;
      const int r = 1 + (j >> 1);
      idx = r * WP + ((j & 1) ? (WP - 1) : 0);
    }
    p[idx] = 0.0f;
  }
}
__global__ void k_zero(float* __restrict__ counts, float* __restrict__ sumsq) {
  const int t = blockIdx.x * 256 + threadIdx.x;
  if (t < 1024) counts[t] = 0.0f;
  if (t == 0) sumsq[0] = 0.0f;
}

// ---------------- weight prep ----------------
// [Cout,Cin,K] -> [Cin,K,Cout]  (fp32)
__global__ void k_wt_conv(const float* __restrict__ w, float* __restrict__ wT,
                          int Cin, int Cout, int K) {
  const int n = Cin * Cout * K;
  for (int i = blockIdx.x * 256 + threadIdx.x; i < n; i += gridDim.x * 256) {
    const int co = i % Cout;
    const int k  = (i / Cout) % K;
    const int ci = i / (Cout * K);
    wT[i] = w[((size_t)co * Cin + ci) * K + k];
  }
}
// tconv weight [Cin][Cout][16] -> bf16 wbT[phase][co][ci*4+tap]
__global__ void k_wtb(const float* __restrict__ w, ushort_t* __restrict__ wbT,
                      int Cin, int Cout) {
  const int n = 4 * Cout * Cin * 4;
  for (int i = blockIdx.x * 256 + threadIdx.x; i < n; i += gridDim.x * 256) {
    const int tap = i & 3;
    const int ci  = (i >> 2) % Cin;
    const int co  = ((i >> 2) / Cin) % Cout;
    const int ph  = (i >> 2) / (Cin * Cout);
    const int ey = ph >> 1, ex = ph & 1;
    const int ty = tap >> 1, tx = tap & 1;
    const int kidx = (3 - 2 * ty - ey) * 4 + (3 - 2 * tx - ex);
    wbT[i] = f2b(w[((size_t)ci * Cout + co) * 16 + kidx]);
  }
}
// split fp32 -> bf16 hi + bf16 lo (elementwise, layout preserved)
__global__ void k_wsplit(const float* __restrict__ w, ushort_t* __restrict__ wh,
                         ushort_t* __restrict__ wl, int n) {
  for (int i = blockIdx.x * 256 + threadIdx.x; i < n; i += gridDim.x * 256) {
    const float v = w[i];
    const ushort_t h = f2b(v);
    wh[i] = h;
    wl[i] = f2b(v - b2f(h));
  }
}
// conv3x3 weight [64co][256ci][9t] -> split bf16 [9t][64co][256ci]
__global__ void k_wt3split(const float* __restrict__ w, ushort_t* __restrict__ wh,
                           ushort_t* __restrict__ wl) {
  const int n = 9 * 64 * 256;
  for (int i = blockIdx.x * 256 + threadIdx.x; i < n; i += gridDim.x * 256) {
    const int ci = i & 255;
    const int co = (i >> 8) & 63;
    const int t  = i >> 14;
    const float v = w[((size_t)co * 256 + ci) * 9 + t];
    const ushort_t h = f2b(v);
    wh[i] = h;
    wl[i] = f2b(v - b2f(h));
  }
}
// codebook [1024,64] -> cbT [64][1024] + cnorm[1024]
__global__ void k_cbt(const float* __restrict__ cb, float* __restrict__ cbT,
                      float* __restrict__ cnorm) {
  const int c = blockIdx.x * 256 + threadIdx.x;
  float s = 0.0f;
  for (int ci = 0; ci < 64; ++ci) {
    const float v = cb[(size_t)c * 64 + ci];
    s += v * v;
    cbT[(size_t)ci * 1024 + c] = v;
  }
  cnorm[c] = s;
}

// ---------------- enc0: conv 4x4 s2 p1, Cin=3, staged, PADDED fp32 out ----------
__global__ __launch_bounds__(256) void k_conv4s2_s3(
    const float* __restrict__ in, const float* __restrict__ wT,
    const float* __restrict__ bias, float* __restrict__ out) {
  const int b   = blockIdx.z;
  const int co0 = blockIdx.y << 4;
  const int oy0 = (blockIdx.x >> 2) << 5;
  const int ox0 = (blockIdx.x & 3) << 5;
  const int tid = threadIdx.x;
  const int ty = tid >> 4, tx = tid & 15;
  __shared__ float tin[3][66][67];
  float acc[4][16];
#pragma unroll
  for (int p = 0; p < 4; ++p)
#pragma unroll
    for (int co = 0; co < 16; ++co) acc[p][co] = 0.0f;

  const int iy0 = (oy0 << 1) - 1, ix0 = (ox0 << 1) - 1;
  for (int c = 0; c < 3; ++c) {
    const float* ip = in + (size_t)(b * 3 + c) * 65536;
    for (int j = tid; j < 66 * 66; j += 256) {
      const int r = j / 66, col = j - r * 66;
      const int iy = iy0 + r, ix = ix0 + col;
      float v = 0.0f;
      if ((unsigned)iy < 256u && (unsigned)ix < 256u) v = ip[iy * 256 + ix];
      tin[c][r][col] = v;
    }
  }
  __syncthreads();
#pragma unroll
  for (int c = 0; c < 3; ++c) {
    const float* wp = wT + (size_t)c * 16 * 64 + co0;
#pragma unroll
    for (int ky = 0; ky < 4; ++ky)
#pragma unroll
      for (int kx = 0; kx < 4; ++kx) {
        const float v0 = tin[c][2 * ty + ky][2 * tx + kx];
        const float v1 = tin[c][2 * ty + ky][2 * tx + 32 + kx];
        const float v2 = tin[c][2 * ty + 32 + ky][2 * tx + kx];
        const float v3 = tin[c][2 * ty + 32 + ky][2 * tx + 32 + kx];
        const float* wk = wp + (ky * 4 + kx) * 64;
#pragma unroll
        for (int co = 0; co < 16; ++co) {
          const float wv = wk[co];
          acc[0][co] = fmaf(v0, wv, acc[0][co]);
          acc[1][co] = fmaf(v1, wv, acc[1][co]);
          acc[2][co] = fmaf(v2, wv, acc[2][co]);
          acc[3][co] = fmaf(v3, wv, acc[3][co]);
        }
      }
  }
#pragma unroll
  for (int co = 0; co < 16; ++co) {
    const float bv = bias[co0 + co];
    float* op = out + (size_t)(b * 64 + co0 + co) * 16900;
    op[(size_t)(oy0 + ty + 1) * 130 + ox0 + tx + 1]        = fmaxf(acc[0][co] + bv, 0.0f);
    op[(size_t)(oy0 + ty + 1) * 130 + ox0 + tx + 17]       = fmaxf(acc[1][co] + bv, 0.0f);
    op[(size_t)(oy0 + ty + 17) * 130 + ox0 + tx + 1]       = fmaxf(acc[2][co] + bv, 0.0f);
    op[(size_t)(oy0 + ty + 17) * 130 + ox0 + tx + 17]      = fmaxf(acc[3][co] + bv, 0.0f);
  }
}

// ---------------- split-bf16 MFMA conv 4x4 s2 p1 (encoder; ~fp32 accuracy) ----------------
template <int WSHIFT, int CIN, int COUT, int WP, int INSTRIDE, int WOP, int OUTSTRIDE>
__global__ __launch_bounds__(256) void k_conv4s2_mfma(
    const float* __restrict__ in, const ushort_t* __restrict__ wbh,
    const ushort_t* __restrict__ wbl, const float* __restrict__ bias,
    float* __restrict__ out) {
  constexpr int W = 1 << WSHIFT;
  constexpr int NCH = CIN / 2;  // K-chunk = 32 = 2 ci x 16 taps
  __shared__ __align__(16) short lsAh[64 * 40];
  __shared__ __align__(16) short lsAl[64 * 40];
  __shared__ __align__(16) short lsBh[64 * 40];
  __shared__ __align__(16) short lsBl[64 * 40];

  const int tid = threadIdx.x;
  const int b = blockIdx.z;
  const int co_b0 = blockIdx.y << 6;
  const int pxb0 = blockIdx.x << 6;

  const int spx = tid & 63;
  const int kg  = tid >> 6;
  const int sy = (pxb0 + spx) >> WSHIFT;
  const int sx = (pxb0 + spx) & (W - 1);
  const float* ipa = in + (size_t)(b * CIN + (kg >> 1)) * INSTRIDE
                   + (size_t)(2 * sy + 2 * (kg & 1)) * WP + 2 * sx;
  const ushort_t* wbase_h = wbh + (size_t)(co_b0 + spx) * (CIN * 16) + kg * 8;
  const ushort_t* wbase_l = wbl + (size_t)(co_b0 + spx) * (CIN * 16) + kg * 8;

  const int lane = tid & 63, wid = tid >> 6;
  const int wm = wid & 1, wn = wid >> 1;
  const int arow = lane & 15, ag = lane >> 4;

  f32x4 acc[2][2];
#pragma unroll
  for (int m = 0; m < 2; ++m)
#pragma unroll
    for (int n = 0; n < 2; ++n) acc[m][n] = (f32x4){0.f, 0.f, 0.f, 0.f};

  float pa[8];
  u32x4 pbh, pbl;
  auto loadch = [&](int ch) {
    const float* p = ipa + (size_t)ch * 2 * INSTRIDE;
    pa[0] = p[0];  pa[1] = p[1];      pa[2] = p[2];      pa[3] = p[3];
    pa[4] = p[WP]; pa[5] = p[WP + 1]; pa[6] = p[WP + 2]; pa[7] = p[WP + 3];
    pbh = *(const u32x4*)(wbase_h + (size_t)ch * 32);
    pbl = *(const u32x4*)(wbase_l + (size_t)ch * 32);
  };

  loadch(0);
  for (int ch = 0; ch < NCH; ++ch) {
    __syncthreads();
    u32x4 vh, vl;
#pragma unroll
    for (int j = 0; j < 4; ++j) {
      const ushort_t h0 = f2b(pa[2 * j]);
      const ushort_t h1 = f2b(pa[2 * j + 1]);
      const ushort_t l0 = f2b(pa[2 * j] - b2f(h0));
      const ushort_t l1 = f2b(pa[2 * j + 1] - b2f(h1));
      vh[j] = (uint_t)h0 | ((uint_t)h1 << 16);
      vl[j] = (uint_t)l0 | ((uint_t)l1 << 16);
    }
    *(u32x4*)(&lsAh[spx * 40 + kg * 8]) = vh;
    *(u32x4*)(&lsAl[spx * 40 + kg * 8]) = vl;
    *(u32x4*)(&lsBh[spx * 40 + kg * 8]) = pbh;
    *(u32x4*)(&lsBl[spx * 40 + kg * 8]) = pbl;
    if (ch + 1 < NCH) loadch(ch + 1);
    __syncthreads();
    short8 ah[2], al[2], bh[2], bl[2];
#pragma unroll
    for (int m = 0; m < 2; ++m) {
      ah[m] = *(const short8*)(&lsAh[(wm * 32 + m * 16 + arow) * 40 + ag * 8]);
      al[m] = *(const short8*)(&lsAl[(wm * 32 + m * 16 + arow) * 40 + ag * 8]);
    }
#pragma unroll
    for (int n = 0; n < 2; ++n) {
      bh[n] = *(const short8*)(&lsBh[(wn * 32 + n * 16 + arow) * 40 + ag * 8]);
      bl[n] = *(const short8*)(&lsBl[(wn * 32 + n * 16 + arow) * 40 + ag * 8]);
    }
#pragma unroll
    for (int m = 0; m < 2; ++m)
#pragma unroll
      for (int n = 0; n < 2; ++n) {
        acc[m][n] = __builtin_amdgcn_mfma_f32_16x16x32_bf16(ah[m], bh[n], acc[m][n], 0, 0, 0);
        acc[m][n] = __builtin_amdgcn_mfma_f32_16x16x32_bf16(ah[m], bl[n], acc[m][n], 0, 0, 0);
        acc[m][n] = __builtin_amdgcn_mfma_f32_16x16x32_bf16(al[m], bh[n], acc[m][n], 0, 0, 0);
      }
  }

#pragma unroll
  for (int m = 0; m < 2; ++m)
#pragma unroll
    for (int n = 0; n < 2; ++n) {
      const int col = co_b0 + wn * 32 + n * 16 + arow;
      const float bv = bias[col];
      float* obase = out + (size_t)(b * COUT + col) * OUTSTRIDE;
#pragma unroll
      for (int r = 0; r < 4; ++r) {
        const int pxl = pxb0 + wm * 32 + m * 16 + ag * 4 + r;
        const int yy = pxl >> WSHIFT, xx = pxl & (W - 1);
        obase[(size_t)(yy + 1) * WOP + (xx + 1)] = fmaxf(acc[m][n][r] + bv, 0.0f);
      }
    }
}

// ---------------- FUSED res-block: conv3x3(relu(x)) -> relu -> 1x1 -> +x  ----------
// GEMM1: M=64px N=64co K=2304 (9 taps x 256ci). GEMM2: M=64px N=256 K=64. All split-bf16.
// out[b][256][34][34] (padded interior) = x + w2 @ relu(w3 @ relu(x) + b1) + b2
__global__ __launch_bounds__(512) void k_res_mfma(
    const float* __restrict__ in, const ushort_t* __restrict__ w3h,
    const ushort_t* __restrict__ w3l, const float* __restrict__ b1,
    const ushort_t* __restrict__ w2h, const ushort_t* __restrict__ w2l,
    const float* __restrict__ b2, float* __restrict__ out) {
  __shared__ __align__(16) short smem[10240];
  short* lsAh = smem;
  short* lsAl = smem + 2560;
  short* lsBh = smem + 5120;
  short* lsBl = smem + 7680;

  const int tid = threadIdx.x;
  const int b = blockIdx.z;
  const int pxb0 = blockIdx.x << 6;
  const bool isA = tid < 256;
  const int sidx = tid & 63;
  const int skg  = (tid >> 6) & 3;

  const int py = (pxb0 + sidx) >> 5;
  const int pxx = (pxb0 + sidx) & 31;
  const float* ipa = in + (size_t)b * 256 * 1156 + (size_t)py * 34 + pxx;

  const int lane = tid & 63, wid = tid >> 6;
  const int wm = wid & 1, wn = wid >> 1;
  const int arow = lane & 15, ag = lane >> 4;

  f32x4 acc[2];
  acc[0] = (f32x4){0.f, 0.f, 0.f, 0.f};
  acc[1] = (f32x4){0.f, 0.f, 0.f, 0.f};

  float pa[8];
  u32x4 pbh, pbl;
  auto loadit = [&](int it) {
    const int t = it >> 3, ck = it & 7;
    if (isA) {
      const int dy = t / 3, dx = t - 3 * (t / 3);
      const float* p = ipa + (size_t)(ck * 32 + skg * 8) * 1156 + dy * 34 + dx;
#pragma unroll
      for (int j = 0; j < 8; ++j) pa[j] = p[(size_t)j * 1156];
    } else {
      const ushort_t* ph = w3h + ((size_t)(t * 64 + sidx) << 8) + ck * 32 + skg * 8;
      const ushort_t* pl = w3l + ((size_t)(t * 64 + sidx) << 8) + ck * 32 + skg * 8;
      pbh = *(const u32x4*)ph;
      pbl = *(const u32x4*)pl;
    }
  };

  loadit(0);
  for (int it = 0; it < 72; ++it) {
    __syncthreads();
    if (isA) {
      u32x4 vh, vl;
#pragma unroll
      for (int j = 0; j < 4; ++j) {
        const float v0 = fmaxf(pa[2 * j], 0.0f);
        const float v1 = fmaxf(pa[2 * j + 1], 0.0f);
        const ushort_t h0 = f2b(v0);
        const ushort_t h1 = f2b(v1);
        const ushort_t l0 = f2b(v0 - b2f(h0));
        const ushort_t l1 = f2b(v1 - b2f(h1));
        vh[j] = (uint_t)h0 | ((uint_t)h1 << 16);
        vl[j] = (uint_t)l0 | ((uint_t)l1 << 16);
      }
      *(u32x4*)(&lsAh[sidx * 40 + skg * 8]) = vh;
      *(u32x4*)(&lsAl[sidx * 40 + skg * 8]) = vl;
    } else {
      *(u32x4*)(&lsBh[sidx * 40 + skg * 8]) = pbh;
      *(u32x4*)(&lsBl[sidx * 40 + skg * 8]) = pbl;
    }
    if (it + 1 < 72) loadit(it + 1);
    __syncthreads();
    short8 ah[2], al[2];
#pragma unroll
    for (int m = 0; m < 2; ++m) {
      ah[m] = *(const short8*)(&lsAh[(wm * 32 + m * 16 + arow) * 40 + ag * 8]);
      al[m] = *(const short8*)(&lsAl[(wm * 32 + m * 16 + arow) * 40 + ag * 8]);
    }
    const short8 bh = *(const short8*)(&lsBh[(wn * 16 + arow) * 40 + ag * 8]);
    const short8 bl = *(const short8*)(&lsBl[(wn * 16 + arow) * 40 + ag * 8]);
#pragma unroll
    for (int m = 0; m < 2; ++m) {
      acc[m] = __builtin_amdgcn_mfma_f32_16x16x32_bf16(ah[m], bh, acc[m], 0, 0, 0);
      acc[m] = __builtin_amdgcn_mfma_f32_16x16x32_bf16(ah[m], bl, acc[m], 0, 0, 0);
      acc[m] = __builtin_amdgcn_mfma_f32_16x16x32_bf16(al[m], bh, acc[m], 0, 0, 0);
    }
  }

  // ---- store relu(h + b1) as split bf16 into smem [64px][72] (hi @0, lo @4608) ----
  __syncthreads();
  {
    const float bv = b1[wn * 16 + arow];
    short* hh = smem;
    short* hl = smem + 4608;
#pragma unroll
    for (int m = 0; m < 2; ++m)
#pragma unroll
      for (int r = 0; r < 4; ++r) {
        const int pxl = wm * 32 + m * 16 + ag * 4 + r;
        const float v = fmaxf(acc[m][r] + bv, 0.0f);
        const ushort_t h = f2b(v);
        hh[pxl * 72 + wn * 16 + arow] = (short)h;
        hl[pxl * 72 + wn * 16 + arow] = (short)f2b(v - b2f(h));
      }
  }
  __syncthreads();

  // ---- GEMM2: M=64px N=256co K=64, B from global (L1-hot), + residual + write ----
  const int m2 = wid & 3;
  const int nh = wid >> 2;
  const short* hh = smem;
  const short* hl = smem + 4608;
  short8 a2h[2], a2l[2];
#pragma unroll
  for (int c = 0; c < 2; ++c) {
    a2h[c] = *(const short8*)(&hh[(m2 * 16 + arow) * 72 + c * 32 + ag * 8]);
    a2l[c] = *(const short8*)(&hl[(m2 * 16 + arow) * 72 + c * 32 + ag * 8]);
  }
#pragma unroll
  for (int j = 0; j < 8; ++j) {
    const int col2 = (nh * 8 + j) * 16 + arow;
    f32x4 acc2 = (f32x4){0.f, 0.f, 0.f, 0.f};
#pragma unroll
    for (int c = 0; c < 2; ++c) {
      const short8 b2h_ = *(const short8*)(w2h + (size_t)col2 * 64 + c * 32 + ag * 8);
      const short8 b2l_ = *(const short8*)(w2l + (size_t)col2 * 64 + c * 32 + ag * 8);
      acc2 = __builtin_amdgcn_mfma_f32_16x16x32_bf16(a2h[c], b2h_, acc2, 0, 0, 0);
      acc2 = __builtin_amdgcn_mfma_f32_16x16x32_bf16(a2h[c], b2l_, acc2, 0, 0, 0);
      acc2 = __builtin_amdgcn_mfma_f32_16x16x32_bf16(a2l[c], b2h_, acc2, 0, 0, 0);
    }
    const float bv2 = b2[col2];
    float* obase = out + (size_t)(b * 256 + col2) * 1156;
    const float* rbase = in + (size_t)(b * 256 + col2) * 1156;
#pragma unroll
    for (int r = 0; r < 4; ++r) {
      const int px = pxb0 + m2 * 16 + ag * 4 + r;
      const int yy = px >> 5, xx = px & 31;
      const int idx = (yy + 1) * 34 + xx + 1;
      obase[idx] = acc2[r] + bv2 + rbase[idx];
    }
  }
}

// ---------------- conv1x1 px-parallel; pad-aware in/out ----------
template <int IN_RELU, int HAS_RES, int IN_PAD, int OUT_PAD>
__global__ __launch_bounds__(256) void k_conv1x1_px(
    const float* __restrict__ in, const float* __restrict__ wT,
    const float* __restrict__ bias, const float* __restrict__ res,
    float* __restrict__ out, int Cin, int Cout) {
  const int b   = blockIdx.z;
  const int co0 = blockIdx.y << 4;
  const int px  = blockIdx.x * 256 + threadIdx.x;
  const int ppad = 35 + px + 2 * (px >> 5);
  const int ioff = IN_PAD ? ppad : px;
  const int istr = IN_PAD ? 1156 : 1024;
  const int ooff = OUT_PAD ? ppad : px;
  const int ostr = OUT_PAD ? 1156 : 1024;
  float acc[16];
#pragma unroll
  for (int co = 0; co < 16; ++co) acc[co] = 0.0f;
  const float* ip = in + (size_t)b * Cin * istr + ioff;
  const float* wp = wT + co0;
  for (int ci = 0; ci < Cin; ++ci) {
    float v = *ip;
    if (IN_RELU) v = fmaxf(v, 0.0f);
    ip += istr;
#pragma unroll
    for (int co = 0; co < 16; ++co) acc[co] = fmaf(v, wp[co], acc[co]);
    wp += Cout;
  }
  float* op = out + (size_t)(b * Cout + co0) * ostr + ooff;
  const float* rp = res + (size_t)(b * Cout + co0) * ostr + ooff;
#pragma unroll
  for (int co = 0; co < 16; ++co) {
    float r = acc[co] + bias[co0 + co];
    if (HAS_RES) r += rp[(size_t)co * ostr];
    op[(size_t)co * ostr] = r;
  }
}

// ---------------- MFMA bf16 tconv, reg-prefetch, GRP chunks (K=32*GRP) per barrier ---------
template <int PXB, int COB, int WSHIFT, int CIN, int COUT, int WP,
          int INSTRIDE, int WOP, int OUTSTRIDE, int FINAL, int GRP>
__global__ __launch_bounds__(256) void k_tconv_mfma(
    const float* __restrict__ in, const ushort_t* __restrict__ wbT,
    const float* __restrict__ bias, const float* __restrict__ ow,
    const float* __restrict__ ob, float* __restrict__ out) {
  constexpr int W = 1 << WSHIFT;
  constexpr int NCH = CIN / 8;
  constexpr int NGRP = NCH / GRP;
  constexpr int PXSH = (PXB == 64) ? 6 : 7;
  constexpr int COSH = (COB == 64) ? 6 : 5;
  constexpr int NKG = (PXB * 4) / 256;
  constexpr int KGSTEP = 256 / PXB;
  __shared__ __align__(16) short lsA[GRP][PXB * 40];
  __shared__ __align__(16) short lsB[GRP][COB * 40];
  __shared__ float pxco[FINAL ? PXB : 1][33];

  const int tid = threadIdx.x;
  const int b = blockIdx.z;
  const int phase = blockIdx.y & 3;
  const int ey = phase >> 1, ex = phase & 1;
  const int co_b0 = (blockIdx.y >> 2) * COB;
  const int pxb0 = blockIdx.x * PXB;

  const int spx = tid & (PXB - 1);
  const int kg0 = tid >> PXSH;
  const int sy = (pxb0 + spx) >> WSHIFT;
  const int sx = (pxb0 + spx) & (W - 1);
  const float* ipa = in + (size_t)b * CIN * INSTRIDE + (size_t)(sy + ey) * WP + (sx + ex);
  const int sco = tid & (COB - 1);
  const int skg = tid >> COSH;
  const bool bstage = (tid < COB * 4);
  const ushort_t* wrow = wbT + ((size_t)(phase * COUT + co_b0 + sco) * CIN) * 4;

  const int lane = tid & 63, wid = tid >> 6;
  const int wm = wid % (PXB / 32), wn = wid / (PXB / 32);
  const int arow = lane & 15, ag = lane >> 4;

  f32x4 acc[2][2];
#pragma unroll
  for (int m = 0; m < 2; ++m)
#pragma unroll
    for (int n = 0; n < 2; ++n) acc[m][n] = (f32x4){0.f, 0.f, 0.f, 0.f};

  float pa[GRP][NKG][8];
  u32x4 pb[GRP];
  auto loadgrp = [&](int g) {
#pragma unroll
    for (int c = 0; c < GRP; ++c) {
      const int ch = g * GRP + c;
#pragma unroll
      for (int k = 0; k < NKG; ++k) {
        const float* p = ipa + (size_t)(ch * 8 + (kg0 + k * KGSTEP) * 2) * INSTRIDE;
        const float* q = p + INSTRIDE;
        pa[c][k][0] = p[0]; pa[c][k][1] = p[1]; pa[c][k][2] = p[WP]; pa[c][k][3] = p[WP + 1];
        pa[c][k][4] = q[0]; pa[c][k][5] = q[1]; pa[c][k][6] = q[WP]; pa[c][k][7] = q[WP + 1];
      }
      if (bstage) pb[c] = *(const u32x4*)(wrow + (size_t)ch * 32 + skg * 8);
    }
  };

  loadgrp(0);
  for (int g = 0; g < NGRP; ++g) {
    __syncthreads();
#pragma unroll
    for (int c = 0; c < GRP; ++c) {
#pragma unroll
      for (int k = 0; k < NKG; ++k) {
        u32x4 pk;
        pk[0] = (uint_t)f2b(pa[c][k][0]) | ((uint_t)f2b(pa[c][k][1]) << 16);
        pk[1] = (uint_t)f2b(pa[c][k][2]) | ((uint_t)f2b(pa[c][k][3]) << 16);
        pk[2] = (uint_t)f2b(pa[c][k][4]) | ((uint_t)f2b(pa[c][k][5]) << 16);
        pk[3] = (uint_t)f2b(pa[c][k][6]) | ((uint_t)f2b(pa[c][k][7]) << 16);
        *(u32x4*)(&lsA[c][spx * 40 + (kg0 + k * KGSTEP) * 8]) = pk;
      }
      if (bstage) *(u32x4*)(&lsB[c][sco * 40 + skg * 8]) = pb[c];
    }
    if (g + 1 < NGRP) loadgrp(g + 1);
    __syncthreads();
#pragma unroll
    for (int c = 0; c < GRP; ++c) {
      const short8 a0 = *(const short8*)(&lsA[c][(wm * 32 + arow) * 40 + ag * 8]);
      const short8 a1 = *(const short8*)(&lsA[c][(wm * 32 + 16 + arow) * 40 + ag * 8]);
      const short8 b0 = *(const short8*)(&lsB[c][(wn * 32 + arow) * 40 + ag * 8]);
      const short8 b1 = *(const short8*)(&lsB[c][(wn * 32 + 16 + arow) * 40 + ag * 8]);
      acc[0][0] = __builtin_amdgcn_mfma_f32_16x16x32_bf16(a0, b0, acc[0][0], 0, 0, 0);
      acc[0][1] = __builtin_amdgcn_mfma_f32_16x16x32_bf16(a0, b1, acc[0][1], 0, 0, 0);
      acc[1][0] = __builtin_amdgcn_mfma_f32_16x16x32_bf16(a1, b0, acc[1][0], 0, 0, 0);
      acc[1][1] = __builtin_amdgcn_mfma_f32_16x16x32_bf16(a1, b1, acc[1][1], 0, 0, 0);
    }
  }

  if constexpr (!FINAL) {
#pragma unroll
    for (int m = 0; m < 2; ++m)
#pragma unroll
      for (int n = 0; n < 2; ++n) {
        const int col = co_b0 + wn * 32 + n * 16 + arow;
        const float bv = bias[col];
        float* obase = out + (size_t)(b * COUT + col) * OUTSTRIDE;
#pragma unroll
        for (int r = 0; r < 4; ++r) {
          const int pxl = pxb0 + wm * 32 + m * 16 + ag * 4 + r;
          const int yy = pxl >> WSHIFT, xx = pxl & (W - 1);
          obase[(size_t)(2 * yy + ey + 1) * WOP + (2 * xx + ex + 1)] =
              fmaxf(acc[m][n][r] + bv, 0.0f);
        }
      }
  } else {
#pragma unroll
    for (int m = 0; m < 2; ++m)
#pragma unroll
      for (int n = 0; n < 2; ++n) {
        const int col = wn * 32 + n * 16 + arow;
        const float bv = bias[col];
#pragma unroll
        for (int r = 0; r < 4; ++r) {
          const int pxl = wm * 32 + m * 16 + ag * 4 + r;
          pxco[pxl][col] = fmaxf(acc[m][n][r] + bv, 0.0f);
        }
      }
    __syncthreads();
    if (tid < PXB) {
      const int pxg = pxb0 + tid;
      const int yy = pxg >> WSHIFT, xx = pxg & (W - 1);
      const int oy = 2 * yy + ey, ox = 2 * xx + ex;
      float o0 = ob[0], o1 = ob[1], o2 = ob[2];
#pragma unroll
      for (int co = 0; co < 32; ++co) {
        const float v = pxco[tid][co];
        o0 = fmaf(ow[co], v, o0);
        o1 = fmaf(ow[32 + co], v, o1);
        o2 = fmaf(ow[64 + co], v, o2);
      }
      out[((size_t)(b * 3 + 0) * 256 + oy) * 256 + ox] = o0;
      out[((size_t)(b * 3 + 1) * 256 + oy) * 256 + ox] = o1;
      out[((size_t)(b * 3 + 2) * 256 + oy) * 256 + ox] = o2;
    }
  }
}

// ---------------- VQ (fp32 exact) ----------------
__global__ __launch_bounds__(256) void k_vq(
    const float* __restrict__ zlat, const float* __restrict__ cbT,
    const float* __restrict__ cnorm, const float* __restrict__ cb,
    float* __restrict__ q, float* __restrict__ counts, float* __restrict__ sumsq) {
  const int tid = threadIdx.x;
  const int px0 = blockIdx.x << 4;
  const int b   = px0 >> 10;
  const int pl0 = px0 & 1023;
  __shared__ float zT[64][17];
  __shared__ float rd[16][256];
  __shared__ int   ri[16][256];
  for (int j = tid; j < 1024; j += 256) {
    const int ci = j >> 4, p = j & 15;
    zT[ci][p] = zlat[(size_t)(b * 64 + ci) * 1024 + pl0 + p];
  }
  __syncthreads();
  float dot[4][16];
#pragma unroll
  for (int k = 0; k < 4; ++k)
#pragma unroll
    for (int p = 0; p < 16; ++p) dot[k][p] = 0.0f;
  for (int ci = 0; ci < 64; ++ci) {
    float z[16];
#pragma unroll
    for (int p = 0; p < 16; ++p) z[p] = zT[ci][p];
#pragma unroll
    for (int k = 0; k < 4; ++k) {
      const float cv = cbT[(size_t)ci * 1024 + (k << 8) + tid];
#pragma unroll
      for (int p = 0; p < 16; ++p) dot[k][p] = fmaf(cv, z[p], dot[k][p]);
    }
  }
  float bd[16]; int bi[16];
#pragma unroll
  for (int p = 0; p < 16; ++p) { bd[p] = 3.4e38f; bi[p] = 0; }
#pragma unroll
  for (int k = 0; k < 4; ++k) {
    const int c = (k << 8) + tid;
    const float cn = cnorm[c];
#pragma unroll
    for (int p = 0; p < 16; ++p) {
      const float d = cn - 2.0f * dot[k][p];
      if (d < bd[p]) { bd[p] = d; bi[p] = c; }
    }
  }
#pragma unroll
  for (int p = 0; p < 16; ++p) { rd[p][tid] = bd[p]; ri[p][tid] = bi[p]; }
  __syncthreads();
  for (int s = 128; s >= 1; s >>= 1) {
    if (tid < s) {
#pragma unroll
      for (int p = 0; p < 16; ++p) {
        const float d2 = rd[p][tid + s]; const int i2 = ri[p][tid + s];
        const float d1 = rd[p][tid];     const int i1 = ri[p][tid];
        if (d2 < d1 || (d2 == d1 && i2 < i1)) { rd[p][tid] = d2; ri[p][tid] = i2; }
      }
    }
    __syncthreads();
  }
  if (tid < 16) atomicAdd(&counts[ri[tid][0]], 1.0f);
  const int p    = tid >> 4;
  const int best = ri[p][0];
  const int cb0  = (tid & 15) << 2;
  float ss = 0.0f;
  float* qp = q + (size_t)b * 65536 + pl0 + p;
#pragma unroll
  for (int cc = 0; cc < 4; ++cc) {
    const int ci = cb0 + cc;
    const float qv = cb[(size_t)best * 64 + ci];
    const float zv = zT[ci][p];
    const float df = qv - zv;
    ss += df * df;
    qp[(size_t)ci * 1024] = qv;
  }
#pragma unroll
  for (int o = 32; o > 0; o >>= 1) ss += __shfl_down(ss, o);
  if ((tid & 63) == 0) atomicAdd(sumsq, ss);
}

__global__ void k_final(const float* __restrict__ counts, const float* __restrict__ sumsq,
                        float* __restrict__ out2) {
  const int tid = threadIdx.x;
  float h = 0.0f;
  for (int k = tid; k < 1024; k += 256) {
    const float pr = counts[k] * (1.0f / 32768.0f);
    h -= pr * logf(pr + 1e-10f);
  }
#pragma unroll
  for (int o = 32; o > 0; o >>= 1) h += __shfl_down(h, o);
  __shared__ float hs[4];
  if ((tid & 63) == 0) hs[tid >> 6] = h;
  __syncthreads();
  if (tid == 0) {
    out2[0] = 1.25f * sumsq[0] * (1.0f / 2097152.0f);
    out2[1] = expf(hs[0] + hs[1] + hs[2] + hs[3]);
  }
}

// ---------------- launcher ----------------
extern "C" void kernel_launch(void* const* d_in, const int* in_sizes, int n_in,
                              void* d_out, int out_size, void* d_ws, size_t ws_size,
                              hipStream_t stream) {
  const float* x        = (const float*)d_in[0];
  const float* enc_w0   = (const float*)d_in[1];
  const float* enc_b0   = (const float*)d_in[2];
  const float* enc_w1   = (const float*)d_in[3];
  const float* enc_b1   = (const float*)d_in[4];
  const float* enc_w2   = (const float*)d_in[5];
  const float* enc_b2   = (const float*)d_in[6];
  const float* er0w1    = (const float*)d_in[7];
  const float* er0b1    = (const float*)d_in[8];
  const float* er0w2    = (const float*)d_in[9];
  const float* er0b2    = (const float*)d_in[10];
  const float* er1w1    = (const float*)d_in[11];
  const float* er1b1    = (const float*)d_in[12];
  const float* er1w2    = (const float*)d_in[13];
  const float* er1b2    = (const float*)d_in[14];
  const float* eadj_w   = (const float*)d_in[15];
  const float* eadj_b   = (const float*)d_in[16];
  const float* codebook = (const float*)d_in[17];
  const float* dadj_w   = (const float*)d_in[18];
  const float* dadj_b   = (const float*)d_in[19];
  const float* dr0w1    = (const float*)d_in[20];
  const float* dr0b1    = (const float*)d_in[21];
  const float* dr0w2    = (const float*)d_in[22];
  const float* dr0b2    = (const float*)d_in[23];
  const float* dr1w1    = (const float*)d_in[24];
  const float* dr1b1    = (const float*)d_in[25];
  const float* dr1w2    = (const float*)d_in[26];
  const float* dr1b2    = (const float*)d_in[27];
  const float* tw0      = (const float*)d_in[28];
  const float* tb0      = (const float*)d_in[29];
  const float* tw1      = (const float*)d_in[30];
  const float* tb1      = (const float*)d_in[31];
  const float* tw2      = (const float*)d_in[32];
  const float* tb2      = (const float*)d_in[33];
  const float* out_w    = (const float*)d_in[34];
  const float* out_b    = (const float*)d_in[35];

  float* ws = (float*)d_ws;
  float* A      = ws + A_OFF;
  float* Bb     = ws + B_OFF;
  float* C      = ws + C_OFF;
  float* Dq     = ws + D_OFF;
  float* E      = ws + E_OFF;
  float* Q      = ws + Q_OFF;
  float* cbT    = ws + CBT_OFF;
  float* cnorm  = ws + CNORM_OFF;
  float* counts = ws + COUNTS_OFF;
  float* sumsq  = ws + SUMSQ_OFF;

  size_t o = WT_OFF;
  float* wt_enc0  = ws + o; o += (size_t)3 * 16 * 64;
  float* wt_eadj  = ws + o; o += (size_t)256 * 64;
  float* wt_dadj  = ws + o; o += (size_t)64 * 256;
  // bf16 tconv weights
  ushort_t* wbT0 = (ushort_t*)(ws + o); o += 262144;  // 4*128*256*4 u16 = 524288
  ushort_t* wbT1 = (ushort_t*)(ws + o); o += 65536;   // 4*64*128*4  u16 = 131072
  ushort_t* wbT2 = (ushort_t*)(ws + o); o += 16384;   // 4*32*64*4   u16 = 32768
  // split bf16 encoder conv weights ([co][ci][16] layout preserved)
  ushort_t* wsh1 = (ushort_t*)(ws + o); o += 65536;   // 128*64*16 u16
  ushort_t* wsl1 = (ushort_t*)(ws + o); o += 65536;
  ushort_t* wsh2 = (ushort_t*)(ws + o); o += 262144;  // 256*128*16 u16
  ushort_t* wsl2 = (ushort_t*)(ws + o); o += 262144;
  // split bf16 conv3x3 weights [9t][64co][256ci], 147456 u16 each
  ushort_t* w3h_er0 = (ushort_t*)(ws + o); o += 73728;
  ushort_t* w3l_er0 = (ushort_t*)(ws + o); o += 73728;
  ushort_t* w3h_er1 = (ushort_t*)(ws + o); o += 73728;
  ushort_t* w3l_er1 = (ushort_t*)(ws + o); o += 73728;
  ushort_t* w3h_dr0 = (ushort_t*)(ws + o); o += 73728;
  ushort_t* w3l_dr0 = (ushort_t*)(ws + o); o += 73728;
  ushort_t* w3h_dr1 = (ushort_t*)(ws + o); o += 73728;
  ushort_t* w3l_dr1 = (ushort_t*)(ws + o); o += 73728;
  // split bf16 res 1x1 weights [256co][64ci], 16384 u16 each
  ushort_t* w2h_er0 = (ushort_t*)(ws + o); o += 8192;
  ushort_t* w2l_er0 = (ushort_t*)(ws + o); o += 8192;
  ushort_t* w2h_er1 = (ushort_t*)(ws + o); o += 8192;
  ushort_t* w2l_er1 = (ushort_t*)(ws + o); o += 8192;
  ushort_t* w2h_dr0 = (ushort_t*)(ws + o); o += 8192;
  ushort_t* w2l_dr0 = (ushort_t*)(ws + o); o += 8192;
  ushort_t* w2h_dr1 = (ushort_t*)(ws + o); o += 8192;
  ushort_t* w2l_dr1 = (ushort_t*)(ws + o); o += 8192;

  float* fout = (float*)d_out;

  #define GB(n) (((n) + 255) / 256)
  // targeted zeroing (replaces bulk memsets): counters + halos of A, Bb
  k_zero<<<4, 256, 0, stream>>>(counts, sumsq);
  k_halo<<<2048, 64, 0, stream>>>(A, 130, 130);
  k_halo<<<4096, 64, 0, stream>>>(Bb, 66, 66);

  k_wt_conv<<<GB(3 * 64 * 16), 256, 0, stream>>>(enc_w0, wt_enc0, 3, 64, 16);
  k_wt_conv<<<GB(256 * 64), 256, 0, stream>>>(eadj_w, wt_eadj, 256, 64, 1);
  k_wt_conv<<<GB(64 * 256), 256, 0, stream>>>(dadj_w, wt_dadj, 64, 256, 1);
  k_wtb<<<GB(524288), 256, 0, stream>>>(tw0, wbT0, 256, 128);
  k_wtb<<<GB(131072), 256, 0, stream>>>(tw1, wbT1, 128, 64);
  k_wtb<<<GB(32768), 256, 0, stream>>>(tw2, wbT2, 64, 32);
  k_wsplit<<<GB(131072), 256, 0, stream>>>(enc_w1, wsh1, wsl1, 131072);
  k_wsplit<<<GB(524288), 256, 0, stream>>>(enc_w2, wsh2, wsl2, 524288);
  k_wt3split<<<GB(147456), 256, 0, stream>>>(er0w1, w3h_er0, w3l_er0);
  k_wt3split<<<GB(147456), 256, 0, stream>>>(er1w1, w3h_er1, w3l_er1);
  k_wt3split<<<GB(147456), 256, 0, stream>>>(dr0w1, w3h_dr0, w3l_dr0);
  k_wt3split<<<GB(147456), 256, 0, stream>>>(dr1w1, w3h_dr1, w3l_dr1);
  k_wsplit<<<GB(16384), 256, 0, stream>>>(er0w2, w2h_er0, w2l_er0, 16384);
  k_wsplit<<<GB(16384), 256, 0, stream>>>(er1w2, w2h_er1, w2l_er1, 16384);
  k_wsplit<<<GB(16384), 256, 0, stream>>>(dr0w2, w2h_dr0, w2l_dr0, 16384);
  k_wsplit<<<GB(16384), 256, 0, stream>>>(dr1w2, w2h_dr1, w2l_dr1, 16384);
  k_cbt<<<4, 256, 0, stream>>>(codebook, cbT, cnorm);

  // ---------- encoder (split-bf16 MFMA ~ fp32 accuracy; protects VQ argmin) ----------
  k_conv4s2_s3<<<dim3(16, 4, 32), 256, 0, stream>>>(x, wt_enc0, enc_b0, A);
  k_conv4s2_mfma<6, 64, 128, 130, 16900, 66, 4356>
      <<<dim3(64, 2, 32), 256, 0, stream>>>(A, wsh1, wsl1, enc_b1, Bb);
  // A now dead -> zero C/Dq halos (for enc2 / res outputs)
  k_halo<<<8192, 64, 0, stream>>>(C, 34, 34);
  k_halo<<<8192, 64, 0, stream>>>(Dq, 34, 34);
  k_conv4s2_mfma<5, 128, 256, 66, 4356, 34, 1156>
      <<<dim3(16, 4, 32), 256, 0, stream>>>(Bb, wsh2, wsl2, enc_b2, C);
  k_res_mfma<<<dim3(16, 1, 32), 512, 0, stream>>>(C, w3h_er0, w3l_er0, er0b1,
                                                  w2h_er0, w2l_er0, er0b2, Dq);
  k_res_mfma<<<dim3(16, 1, 32), 512, 0, stream>>>(Dq, w3h_er1, w3l_er1, er1b1,
                                                  w2h_er1, w2l_er1, er1b2, C);
  k_conv1x1_px<0, 0, 1, 0><<<dim3(4, 4, 32), 256, 0, stream>>>(C, wt_eadj, eadj_b, nullptr, E, 256, 64);
  // ---------- VQ (fp32 exact) ----------
  k_vq<<<2048, 256, 0, stream>>>(E, cbT, cnorm, codebook, Q, counts, sumsq);
  // ---------- decoder ----------
  k_conv1x1_px<0, 0, 0, 1><<<dim3(4, 16, 32), 256, 0, stream>>>(Q, wt_dadj, dadj_b, nullptr, C, 64, 256);
  k_res_mfma<<<dim3(16, 1, 32), 512, 0, stream>>>(C, w3h_dr0, w3l_dr0, dr0b1,
                                                  w2h_dr0, w2l_dr0, dr0b2, Dq);
  k_res_mfma<<<dim3(16, 1, 32), 512, 0, stream>>>(Dq, w3h_dr1, w3l_dr1, dr1b1,
                                                  w2h_dr1, w2l_dr1, dr1b2, C);
  // MFMA bf16 transposed convs (decoder only)
  k_tconv_mfma<64, 64, 5, 256, 128, 34, 1156, 66, 4356, 0, 2>
      <<<dim3(16, 8, 32), 256, 0, stream>>>(C, wbT0, tb0, nullptr, nullptr, Bb);
  // C/D/E/Q dead -> zero A halos (for tconv1 output; region was scribbled by middle phase)
  k_halo<<<2048, 64, 0, stream>>>(A, 130, 130);
  k_tconv_mfma<64, 64, 6, 128, 64, 66, 4356, 130, 16900, 0, 2>
      <<<dim3(64, 4, 32), 256, 0, stream>>>(Bb, wbT1, tb1, nullptr, nullptr, A);
  k_tconv_mfma<128, 32, 7, 64, 32, 130, 16900, 0, 0, 1, 1>
      <<<dim3(128, 4, 32), 256, 0, stream>>>(A, wbT2, tb2, out_w, out_b, fout);
  k_final<<<1, 256, 0, stream>>>(counts, sumsq, fout + 6291456);
  #undef GB
}

// Round 15
// 1668.972 us; speedup vs baseline: 1.0622x; 1.0622x over previous
//
#include <hip/hip_runtime.h>
#include <math.h>

typedef __attribute__((ext_vector_type(4))) float f32x4;
typedef __attribute__((ext_vector_type(8))) short short8;
typedef __attribute__((ext_vector_type(4))) unsigned int u32x4;
typedef unsigned short ushort_t;
typedef unsigned int uint_t;

// ---------------- workspace layout (float offsets), lifetime-packed, PADDED activations ----
static const size_t A_OFF      = 0;
static const size_t C_OFF      = 0;
static const size_t D_OFF      = 9469952;
static const size_t E_OFF      = 18939904;
static const size_t Q_OFF      = 21037056;
static const size_t B_OFF      = 34611200;
static const size_t CBT_OFF    = 52453376;  // 64*1024
static const size_t CNORM_OFF  = 52518912;  // 1024
static const size_t COUNTS_OFF = 52519936;  // 1024
static const size_t SUMSQ_OFF  = 52520960;  // 1 (+3)
static const size_t WT_OFF     = 52520964;  // transposed weights + bf16/split weights

__device__ __forceinline__ ushort_t f2b(float f) {
  uint_t u = __float_as_uint(f);
  uint_t r = (u + 0x7FFFu + ((u >> 16) & 1u)) >> 16;
  return (ushort_t)r;
}
__device__ __forceinline__ float b2f(ushort_t h) {
  return __uint_as_float(((uint_t)h) << 16);
}

// ---------------- utility: zero pad ring of one padded plane ----------------
__global__ void k_halo(float* __restrict__ buf, int HP, int WP) {
  const int plane = blockIdx.x;
  float* p = buf + (size_t)plane * HP * WP;
  const int ring = 2 * (HP + WP) - 4;
  for (int i = threadIdx.x; i < ring; i += blockDim.x) {
    int idx;
    if (i < WP) idx = i;
    else if (i < 2 * WP) idx = (HP - 1) * WP + (i - WP);
    else {
      const int j = i - 2 * WP;
      const int r = 1 + (j >> 1);
      idx = r * WP + ((j & 1) ? (WP - 1) : 0);
    }
    p[idx] = 0.0f;
  }
}
__global__ void k_zero(float* __restrict__ counts, float* __restrict__ sumsq) {
  const int t = blockIdx.x * 256 + threadIdx.x;
  if (t < 1024) counts[t] = 0.0f;
  if (t == 0) sumsq[0] = 0.0f;
}

// ---------------- weight prep (batched multi-tensor kernels) ----------------
__device__ __forceinline__ void wt_conv_body(const float* w, float* wT,
                                             int Cin, int Cout, int K) {
  const int n = Cin * Cout * K;
  for (int i = blockIdx.x * 256 + threadIdx.x; i < n; i += gridDim.x * 256) {
    const int co = i % Cout;
    const int k  = (i / Cout) % K;
    const int ci = i / (Cout * K);
    wT[i] = w[((size_t)co * Cin + ci) * K + k];
  }
}
// y: 0=enc0(3,64,16) 1=eadj(256,64,1) 2=dadj(64,256,1)
__global__ void k_wt_conv_multi(const float* w0, float* o0, const float* w1, float* o1,
                                const float* w2, float* o2) {
  if (blockIdx.y == 0) wt_conv_body(w0, o0, 3, 64, 16);
  else if (blockIdx.y == 1) wt_conv_body(w1, o1, 256, 64, 1);
  else wt_conv_body(w2, o2, 64, 256, 1);
}
__device__ __forceinline__ void wtb_body(const float* w, ushort_t* wbT,
                                         int Cin, int Cout) {
  const int n = 4 * Cout * Cin * 4;
  for (int i = blockIdx.x * 256 + threadIdx.x; i < n; i += gridDim.x * 256) {
    const int tap = i & 3;
    const int ci  = (i >> 2) % Cin;
    const int co  = ((i >> 2) / Cin) % Cout;
    const int ph  = (i >> 2) / (Cin * Cout);
    const int ey = ph >> 1, ex = ph & 1;
    const int ty = tap >> 1, tx = tap & 1;
    const int kidx = (3 - 2 * ty - ey) * 4 + (3 - 2 * tx - ex);
    wbT[i] = f2b(w[((size_t)ci * Cout + co) * 16 + kidx]);
  }
}
__global__ void k_wtb_multi(const float* t0, ushort_t* o0, const float* t1, ushort_t* o1,
                            const float* t2, ushort_t* o2) {
  if (blockIdx.y == 0) wtb_body(t0, o0, 256, 128);
  else if (blockIdx.y == 1) wtb_body(t1, o1, 128, 64);
  else wtb_body(t2, o2, 64, 32);
}
__device__ __forceinline__ void wsplit_body(const float* w, ushort_t* wh,
                                            ushort_t* wl, int n) {
  for (int i = blockIdx.x * 256 + threadIdx.x; i < n; i += gridDim.x * 256) {
    const float v = w[i];
    const ushort_t h = f2b(v);
    wh[i] = h;
    wl[i] = f2b(v - b2f(h));
  }
}
__global__ void k_wsplit_enc(const float* w1, ushort_t* h1, ushort_t* l1,
                             const float* w2, ushort_t* h2, ushort_t* l2) {
  if (blockIdx.y == 0) wsplit_body(w1, h1, l1, 131072);
  else wsplit_body(w2, h2, l2, 524288);
}
__global__ void k_wsplit_w2m(const float* a, ushort_t* ah, ushort_t* al,
                             const float* b, ushort_t* bh, ushort_t* bl,
                             const float* c, ushort_t* ch, ushort_t* cl,
                             const float* d, ushort_t* dh, ushort_t* dl) {
  if (blockIdx.y == 0) wsplit_body(a, ah, al, 16384);
  else if (blockIdx.y == 1) wsplit_body(b, bh, bl, 16384);
  else if (blockIdx.y == 2) wsplit_body(c, ch, cl, 16384);
  else wsplit_body(d, dh, dl, 16384);
}
__device__ __forceinline__ void wt3_body(const float* w, ushort_t* wh, ushort_t* wl) {
  const int n = 9 * 64 * 256;
  for (int i = blockIdx.x * 256 + threadIdx.x; i < n; i += gridDim.x * 256) {
    const int ci = i & 255;
    const int co = (i >> 8) & 63;
    const int t  = i >> 14;
    const float v = w[((size_t)co * 256 + ci) * 9 + t];
    const ushort_t h = f2b(v);
    wh[i] = h;
    wl[i] = f2b(v - b2f(h));
  }
}
__global__ void k_wt3split_multi(const float* a, ushort_t* ah, ushort_t* al,
                                 const float* b, ushort_t* bh, ushort_t* bl,
                                 const float* c, ushort_t* ch, ushort_t* cl,
                                 const float* d, ushort_t* dh, ushort_t* dl) {
  if (blockIdx.y == 0) wt3_body(a, ah, al);
  else if (blockIdx.y == 1) wt3_body(b, bh, bl);
  else if (blockIdx.y == 2) wt3_body(c, ch, cl);
  else wt3_body(d, dh, dl);
}
// codebook [1024,64] -> cbT [64][1024] + cnorm[1024]
__global__ void k_cbt(const float* __restrict__ cb, float* __restrict__ cbT,
                      float* __restrict__ cnorm) {
  const int c = blockIdx.x * 256 + threadIdx.x;
  float s = 0.0f;
  for (int ci = 0; ci < 64; ++ci) {
    const float v = cb[(size_t)c * 64 + ci];
    s += v * v;
    cbT[(size_t)ci * 1024 + c] = v;
  }
  cnorm[c] = s;
}

// ---------------- enc0: conv 4x4 s2 p1, Cin=3, staged, PADDED fp32 out ----------
__global__ __launch_bounds__(256) void k_conv4s2_s3(
    const float* __restrict__ in, const float* __restrict__ wT,
    const float* __restrict__ bias, float* __restrict__ out) {
  const int b   = blockIdx.z;
  const int co0 = blockIdx.y << 4;
  const int oy0 = (blockIdx.x >> 2) << 5;
  const int ox0 = (blockIdx.x & 3) << 5;
  const int tid = threadIdx.x;
  const int ty = tid >> 4, tx = tid & 15;
  __shared__ float tin[3][66][67];
  float acc[4][16];
#pragma unroll
  for (int p = 0; p < 4; ++p)
#pragma unroll
    for (int co = 0; co < 16; ++co) acc[p][co] = 0.0f;

  const int iy0 = (oy0 << 1) - 1, ix0 = (ox0 << 1) - 1;
  for (int c = 0; c < 3; ++c) {
    const float* ip = in + (size_t)(b * 3 + c) * 65536;
    for (int j = tid; j < 66 * 66; j += 256) {
      const int r = j / 66, col = j - r * 66;
      const int iy = iy0 + r, ix = ix0 + col;
      float v = 0.0f;
      if ((unsigned)iy < 256u && (unsigned)ix < 256u) v = ip[iy * 256 + ix];
      tin[c][r][col] = v;
    }
  }
  __syncthreads();
#pragma unroll
  for (int c = 0; c < 3; ++c) {
    const float* wp = wT + (size_t)c * 16 * 64 + co0;
#pragma unroll
    for (int ky = 0; ky < 4; ++ky)
#pragma unroll
      for (int kx = 0; kx < 4; ++kx) {
        const float v0 = tin[c][2 * ty + ky][2 * tx + kx];
        const float v1 = tin[c][2 * ty + ky][2 * tx + 32 + kx];
        const float v2 = tin[c][2 * ty + 32 + ky][2 * tx + kx];
        const float v3 = tin[c][2 * ty + 32 + ky][2 * tx + 32 + kx];
        const float* wk = wp + (ky * 4 + kx) * 64;
#pragma unroll
        for (int co = 0; co < 16; ++co) {
          const float wv = wk[co];
          acc[0][co] = fmaf(v0, wv, acc[0][co]);
          acc[1][co] = fmaf(v1, wv, acc[1][co]);
          acc[2][co] = fmaf(v2, wv, acc[2][co]);
          acc[3][co] = fmaf(v3, wv, acc[3][co]);
        }
      }
  }
#pragma unroll
  for (int co = 0; co < 16; ++co) {
    const float bv = bias[co0 + co];
    float* op = out + (size_t)(b * 64 + co0 + co) * 16900;
    op[(size_t)(oy0 + ty + 1) * 130 + ox0 + tx + 1]        = fmaxf(acc[0][co] + bv, 0.0f);
    op[(size_t)(oy0 + ty + 1) * 130 + ox0 + tx + 17]       = fmaxf(acc[1][co] + bv, 0.0f);
    op[(size_t)(oy0 + ty + 17) * 130 + ox0 + tx + 1]       = fmaxf(acc[2][co] + bv, 0.0f);
    op[(size_t)(oy0 + ty + 17) * 130 + ox0 + tx + 17]      = fmaxf(acc[3][co] + bv, 0.0f);
  }
}

// ---------------- split-bf16 MFMA conv 4x4 s2 p1 (encoder; ~fp32 accuracy) ----------------
template <int WSHIFT, int CIN, int COUT, int WP, int INSTRIDE, int WOP, int OUTSTRIDE>
__global__ __launch_bounds__(256) void k_conv4s2_mfma(
    const float* __restrict__ in, const ushort_t* __restrict__ wbh,
    const ushort_t* __restrict__ wbl, const float* __restrict__ bias,
    float* __restrict__ out) {
  constexpr int W = 1 << WSHIFT;
  constexpr int NCH = CIN / 2;  // K-chunk = 32 = 2 ci x 16 taps
  __shared__ __align__(16) short lsAh[64 * 40];
  __shared__ __align__(16) short lsAl[64 * 40];
  __shared__ __align__(16) short lsBh[64 * 40];
  __shared__ __align__(16) short lsBl[64 * 40];

  const int tid = threadIdx.x;
  const int b = blockIdx.z;
  const int co_b0 = blockIdx.y << 6;
  const int pxb0 = blockIdx.x << 6;

  const int spx = tid & 63;
  const int kg  = tid >> 6;
  const int sy = (pxb0 + spx) >> WSHIFT;
  const int sx = (pxb0 + spx) & (W - 1);
  const float* ipa = in + (size_t)(b * CIN + (kg >> 1)) * INSTRIDE
                   + (size_t)(2 * sy + 2 * (kg & 1)) * WP + 2 * sx;
  const ushort_t* wbase_h = wbh + (size_t)(co_b0 + spx) * (CIN * 16) + kg * 8;
  const ushort_t* wbase_l = wbl + (size_t)(co_b0 + spx) * (CIN * 16) + kg * 8;

  const int lane = tid & 63, wid = tid >> 6;
  const int wm = wid & 1, wn = wid >> 1;
  const int arow = lane & 15, ag = lane >> 4;

  f32x4 acc[2][2];
#pragma unroll
  for (int m = 0; m < 2; ++m)
#pragma unroll
    for (int n = 0; n < 2; ++n) acc[m][n] = (f32x4){0.f, 0.f, 0.f, 0.f};

  float pa[8];
  u32x4 pbh, pbl;
  auto loadch = [&](int ch) {
    const float* p = ipa + (size_t)ch * 2 * INSTRIDE;
    pa[0] = p[0];  pa[1] = p[1];      pa[2] = p[2];      pa[3] = p[3];
    pa[4] = p[WP]; pa[5] = p[WP + 1]; pa[6] = p[WP + 2]; pa[7] = p[WP + 3];
    pbh = *(const u32x4*)(wbase_h + (size_t)ch * 32);
    pbl = *(const u32x4*)(wbase_l + (size_t)ch * 32);
  };

  loadch(0);
  for (int ch = 0; ch < NCH; ++ch) {
    __syncthreads();
    u32x4 vh, vl;
#pragma unroll
    for (int j = 0; j < 4; ++j) {
      const ushort_t h0 = f2b(pa[2 * j]);
      const ushort_t h1 = f2b(pa[2 * j + 1]);
      const ushort_t l0 = f2b(pa[2 * j] - b2f(h0));
      const ushort_t l1 = f2b(pa[2 * j + 1] - b2f(h1));
      vh[j] = (uint_t)h0 | ((uint_t)h1 << 16);
      vl[j] = (uint_t)l0 | ((uint_t)l1 << 16);
    }
    *(u32x4*)(&lsAh[spx * 40 + kg * 8]) = vh;
    *(u32x4*)(&lsAl[spx * 40 + kg * 8]) = vl;
    *(u32x4*)(&lsBh[spx * 40 + kg * 8]) = pbh;
    *(u32x4*)(&lsBl[spx * 40 + kg * 8]) = pbl;
    if (ch + 1 < NCH) loadch(ch + 1);
    __syncthreads();
    short8 ah[2], al[2], bh[2], bl[2];
#pragma unroll
    for (int m = 0; m < 2; ++m) {
      ah[m] = *(const short8*)(&lsAh[(wm * 32 + m * 16 + arow) * 40 + ag * 8]);
      al[m] = *(const short8*)(&lsAl[(wm * 32 + m * 16 + arow) * 40 + ag * 8]);
    }
#pragma unroll
    for (int n = 0; n < 2; ++n) {
      bh[n] = *(const short8*)(&lsBh[(wn * 32 + n * 16 + arow) * 40 + ag * 8]);
      bl[n] = *(const short8*)(&lsBl[(wn * 32 + n * 16 + arow) * 40 + ag * 8]);
    }
#pragma unroll
    for (int m = 0; m < 2; ++m)
#pragma unroll
      for (int n = 0; n < 2; ++n) {
        acc[m][n] = __builtin_amdgcn_mfma_f32_16x16x32_bf16(ah[m], bh[n], acc[m][n], 0, 0, 0);
        acc[m][n] = __builtin_amdgcn_mfma_f32_16x16x32_bf16(ah[m], bl[n], acc[m][n], 0, 0, 0);
        acc[m][n] = __builtin_amdgcn_mfma_f32_16x16x32_bf16(al[m], bh[n], acc[m][n], 0, 0, 0);
      }
  }

#pragma unroll
  for (int m = 0; m < 2; ++m)
#pragma unroll
    for (int n = 0; n < 2; ++n) {
      const int col = co_b0 + wn * 32 + n * 16 + arow;
      const float bv = bias[col];
      float* obase = out + (size_t)(b * COUT + col) * OUTSTRIDE;
#pragma unroll
      for (int r = 0; r < 4; ++r) {
        const int pxl = pxb0 + wm * 32 + m * 16 + ag * 4 + r;
        const int yy = pxl >> WSHIFT, xx = pxl & (W - 1);
        obase[(size_t)(yy + 1) * WOP + (xx + 1)] = fmaxf(acc[m][n][r] + bv, 0.0f);
      }
    }
}

// ---------------- FUSED res-block: conv3x3(relu(x)) -> relu -> 1x1 -> +x  ----------
// GEMM2 epilogue now software-pipelined (B/resid/bias prefetch).
__global__ __launch_bounds__(512) void k_res_mfma(
    const float* __restrict__ in, const ushort_t* __restrict__ w3h,
    const ushort_t* __restrict__ w3l, const float* __restrict__ b1,
    const ushort_t* __restrict__ w2h, const ushort_t* __restrict__ w2l,
    const float* __restrict__ b2, float* __restrict__ out) {
  __shared__ __align__(16) short smem[10240];
  short* lsAh = smem;
  short* lsAl = smem + 2560;
  short* lsBh = smem + 5120;
  short* lsBl = smem + 7680;

  const int tid = threadIdx.x;
  const int b = blockIdx.z;
  const int pxb0 = blockIdx.x << 6;
  const bool isA = tid < 256;
  const int sidx = tid & 63;
  const int skg  = (tid >> 6) & 3;

  const int py = (pxb0 + sidx) >> 5;
  const int pxx = (pxb0 + sidx) & 31;
  const float* ipa = in + (size_t)b * 256 * 1156 + (size_t)py * 34 + pxx;

  const int lane = tid & 63, wid = tid >> 6;
  const int wm = wid & 1, wn = wid >> 1;
  const int arow = lane & 15, ag = lane >> 4;

  f32x4 acc[2];
  acc[0] = (f32x4){0.f, 0.f, 0.f, 0.f};
  acc[1] = (f32x4){0.f, 0.f, 0.f, 0.f};

  float pa[8];
  u32x4 pbh, pbl;
  auto loadit = [&](int it) {
    const int t = it >> 3, ck = it & 7;
    if (isA) {
      const int dy = t / 3, dx = t - 3 * (t / 3);
      const float* p = ipa + (size_t)(ck * 32 + skg * 8) * 1156 + dy * 34 + dx;
#pragma unroll
      for (int j = 0; j < 8; ++j) pa[j] = p[(size_t)j * 1156];
    } else {
      const ushort_t* ph = w3h + ((size_t)(t * 64 + sidx) << 8) + ck * 32 + skg * 8;
      const ushort_t* pl = w3l + ((size_t)(t * 64 + sidx) << 8) + ck * 32 + skg * 8;
      pbh = *(const u32x4*)ph;
      pbl = *(const u32x4*)pl;
    }
  };

  loadit(0);
  for (int it = 0; it < 72; ++it) {
    __syncthreads();
    if (isA) {
      u32x4 vh, vl;
#pragma unroll
      for (int j = 0; j < 4; ++j) {
        const float v0 = fmaxf(pa[2 * j], 0.0f);
        const float v1 = fmaxf(pa[2 * j + 1], 0.0f);
        const ushort_t h0 = f2b(v0);
        const ushort_t h1 = f2b(v1);
        const ushort_t l0 = f2b(v0 - b2f(h0));
        const ushort_t l1 = f2b(v1 - b2f(h1));
        vh[j] = (uint_t)h0 | ((uint_t)h1 << 16);
        vl[j] = (uint_t)l0 | ((uint_t)l1 << 16);
      }
      *(u32x4*)(&lsAh[sidx * 40 + skg * 8]) = vh;
      *(u32x4*)(&lsAl[sidx * 40 + skg * 8]) = vl;
    } else {
      *(u32x4*)(&lsBh[sidx * 40 + skg * 8]) = pbh;
      *(u32x4*)(&lsBl[sidx * 40 + skg * 8]) = pbl;
    }
    if (it + 1 < 72) loadit(it + 1);
    __syncthreads();
    short8 ah[2], al[2];
#pragma unroll
    for (int m = 0; m < 2; ++m) {
      ah[m] = *(const short8*)(&lsAh[(wm * 32 + m * 16 + arow) * 40 + ag * 8]);
      al[m] = *(const short8*)(&lsAl[(wm * 32 + m * 16 + arow) * 40 + ag * 8]);
    }
    const short8 bh = *(const short8*)(&lsBh[(wn * 16 + arow) * 40 + ag * 8]);
    const short8 bl = *(const short8*)(&lsBl[(wn * 16 + arow) * 40 + ag * 8]);
#pragma unroll
    for (int m = 0; m < 2; ++m) {
      acc[m] = __builtin_amdgcn_mfma_f32_16x16x32_bf16(ah[m], bh, acc[m], 0, 0, 0);
      acc[m] = __builtin_amdgcn_mfma_f32_16x16x32_bf16(ah[m], bl, acc[m], 0, 0, 0);
      acc[m] = __builtin_amdgcn_mfma_f32_16x16x32_bf16(al[m], bh, acc[m], 0, 0, 0);
    }
  }

  // ---- store relu(h + b1) as split bf16 into smem [64px][72] (hi @0, lo @4608) ----
  __syncthreads();
  {
    const float bv = b1[wn * 16 + arow];
    short* hh = smem;
    short* hl = smem + 4608;
#pragma unroll
    for (int m = 0; m < 2; ++m)
#pragma unroll
      for (int r = 0; r < 4; ++r) {
        const int pxl = wm * 32 + m * 16 + ag * 4 + r;
        const float v = fmaxf(acc[m][r] + bv, 0.0f);
        const ushort_t h = f2b(v);
        hh[pxl * 72 + wn * 16 + arow] = (short)h;
        hl[pxl * 72 + wn * 16 + arow] = (short)f2b(v - b2f(h));
      }
  }
  __syncthreads();

  // ---- GEMM2: M=64px N=256co K=64, pipelined (prefetch B_{j+1}, resid_j, bias_j) ----
  const int m2 = wid & 3;
  const int nh = wid >> 2;
  const short* hh = smem;
  const short* hl = smem + 4608;
  short8 a2h[2], a2l[2];
#pragma unroll
  for (int c = 0; c < 2; ++c) {
    a2h[c] = *(const short8*)(&hh[(m2 * 16 + arow) * 72 + c * 32 + ag * 8]);
    a2l[c] = *(const short8*)(&hl[(m2 * 16 + arow) * 72 + c * 32 + ag * 8]);
  }
  const int px0 = pxb0 + m2 * 16 + ag * 4;
  const int yy0 = px0 >> 5, xx0 = px0 & 31;  // r=0..3 contiguous within row (ag*4 aligned)
  const int ridx = (yy0 + 1) * 34 + xx0 + 1;

  short8 cbh[2], cbl[2], nbh[2], nbl[2];
  float rv[4], nrv[4], bvc, nbvc;
  auto loadj = [&](int j, short8* oh, short8* ol, float* rr, float* bb) {
    const int col2 = (nh * 8 + j) * 16 + arow;
#pragma unroll
    for (int c = 0; c < 2; ++c) {
      oh[c] = *(const short8*)(w2h + (size_t)col2 * 64 + c * 32 + ag * 8);
      ol[c] = *(const short8*)(w2l + (size_t)col2 * 64 + c * 32 + ag * 8);
    }
    const float* rbase = in + (size_t)(b * 256 + col2) * 1156 + ridx;
#pragma unroll
    for (int r = 0; r < 4; ++r) rr[r] = rbase[r];
    *bb = b2[col2];
  };

  loadj(0, cbh, cbl, rv, &bvc);
#pragma unroll
  for (int j = 0; j < 8; ++j) {
    if (j + 1 < 8) loadj(j + 1, nbh, nbl, nrv, &nbvc);
    f32x4 acc2 = (f32x4){0.f, 0.f, 0.f, 0.f};
#pragma unroll
    for (int c = 0; c < 2; ++c) {
      acc2 = __builtin_amdgcn_mfma_f32_16x16x32_bf16(a2h[c], cbh[c], acc2, 0, 0, 0);
      acc2 = __builtin_amdgcn_mfma_f32_16x16x32_bf16(a2h[c], cbl[c], acc2, 0, 0, 0);
      acc2 = __builtin_amdgcn_mfma_f32_16x16x32_bf16(a2l[c], cbh[c], acc2, 0, 0, 0);
    }
    const int col2 = (nh * 8 + j) * 16 + arow;
    float* obase = out + (size_t)(b * 256 + col2) * 1156 + ridx;
#pragma unroll
    for (int r = 0; r < 4; ++r) obase[r] = acc2[r] + bvc + rv[r];
#pragma unroll
    for (int c = 0; c < 2; ++c) { cbh[c] = nbh[c]; cbl[c] = nbl[c]; }
#pragma unroll
    for (int r = 0; r < 4; ++r) rv[r] = nrv[r];
    bvc = nbvc;
  }
}

// ---------------- conv1x1 px-parallel; pad-aware in/out ----------
template <int IN_RELU, int HAS_RES, int IN_PAD, int OUT_PAD>
__global__ __launch_bounds__(256) void k_conv1x1_px(
    const float* __restrict__ in, const float* __restrict__ wT,
    const float* __restrict__ bias, const float* __restrict__ res,
    float* __restrict__ out, int Cin, int Cout) {
  const int b   = blockIdx.z;
  const int co0 = blockIdx.y << 4;
  const int px  = blockIdx.x * 256 + threadIdx.x;
  const int ppad = 35 + px + 2 * (px >> 5);
  const int ioff = IN_PAD ? ppad : px;
  const int istr = IN_PAD ? 1156 : 1024;
  const int ooff = OUT_PAD ? ppad : px;
  const int ostr = OUT_PAD ? 1156 : 1024;
  float acc[16];
#pragma unroll
  for (int co = 0; co < 16; ++co) acc[co] = 0.0f;
  const float* ip = in + (size_t)b * Cin * istr + ioff;
  const float* wp = wT + co0;
  for (int ci = 0; ci < Cin; ++ci) {
    float v = *ip;
    if (IN_RELU) v = fmaxf(v, 0.0f);
    ip += istr;
#pragma unroll
    for (int co = 0; co < 16; ++co) acc[co] = fmaf(v, wp[co], acc[co]);
    wp += Cout;
  }
  float* op = out + (size_t)(b * Cout + co0) * ostr + ooff;
  const float* rp = res + (size_t)(b * Cout + co0) * ostr + ooff;
#pragma unroll
  for (int co = 0; co < 16; ++co) {
    float r = acc[co] + bias[co0 + co];
    if (HAS_RES) r += rp[(size_t)co * ostr];
    op[(size_t)co * ostr] = r;
  }
}

// ---------------- MFMA bf16 tconv, reg-prefetch, GRP chunks (K=32*GRP) per barrier ---------
template <int PXB, int COB, int WSHIFT, int CIN, int COUT, int WP,
          int INSTRIDE, int WOP, int OUTSTRIDE, int FINAL, int GRP>
__global__ __launch_bounds__(256) void k_tconv_mfma(
    const float* __restrict__ in, const ushort_t* __restrict__ wbT,
    const float* __restrict__ bias, const float* __restrict__ ow,
    const float* __restrict__ ob, float* __restrict__ out) {
  constexpr int W = 1 << WSHIFT;
  constexpr int NCH = CIN / 8;
  constexpr int NGRP = NCH / GRP;
  constexpr int PXSH = (PXB == 64) ? 6 : 7;
  constexpr int COSH = (COB == 64) ? 6 : 5;
  constexpr int NKG = (PXB * 4) / 256;
  constexpr int KGSTEP = 256 / PXB;
  __shared__ __align__(16) short lsA[GRP][PXB * 40];
  __shared__ __align__(16) short lsB[GRP][COB * 40];
  __shared__ float pxco[FINAL ? PXB : 1][33];

  const int tid = threadIdx.x;
  const int b = blockIdx.z;
  const int phase = blockIdx.y & 3;
  const int ey = phase >> 1, ex = phase & 1;
  const int co_b0 = (blockIdx.y >> 2) * COB;
  const int pxb0 = blockIdx.x * PXB;

  const int spx = tid & (PXB - 1);
  const int kg0 = tid >> PXSH;
  const int sy = (pxb0 + spx) >> WSHIFT;
  const int sx = (pxb0 + spx) & (W - 1);
  const float* ipa = in + (size_t)b * CIN * INSTRIDE + (size_t)(sy + ey) * WP + (sx + ex);
  const int sco = tid & (COB - 1);
  const int skg = tid >> COSH;
  const bool bstage = (tid < COB * 4);
  const ushort_t* wrow = wbT + ((size_t)(phase * COUT + co_b0 + sco) * CIN) * 4;

  const int lane = tid & 63, wid = tid >> 6;
  const int wm = wid % (PXB / 32), wn = wid / (PXB / 32);
  const int arow = lane & 15, ag = lane >> 4;

  f32x4 acc[2][2];
#pragma unroll
  for (int m = 0; m < 2; ++m)
#pragma unroll
    for (int n = 0; n < 2; ++n) acc[m][n] = (f32x4){0.f, 0.f, 0.f, 0.f};

  float pa[GRP][NKG][8];
  u32x4 pb[GRP];
  auto loadgrp = [&](int g) {
#pragma unroll
    for (int c = 0; c < GRP; ++c) {
      const int ch = g * GRP + c;
#pragma unroll
      for (int k = 0; k < NKG; ++k) {
        const float* p = ipa + (size_t)(ch * 8 + (kg0 + k * KGSTEP) * 2) * INSTRIDE;
        const float* q = p + INSTRIDE;
        pa[c][k][0] = p[0]; pa[c][k][1] = p[1]; pa[c][k][2] = p[WP]; pa[c][k][3] = p[WP + 1];
        pa[c][k][4] = q[0]; pa[c][k][5] = q[1]; pa[c][k][6] = q[WP]; pa[c][k][7] = q[WP + 1];
      }
      if (bstage) pb[c] = *(const u32x4*)(wrow + (size_t)ch * 32 + skg * 8);
    }
  };

  loadgrp(0);
  for (int g = 0; g < NGRP; ++g) {
    __syncthreads();
#pragma unroll
    for (int c = 0; c < GRP; ++c) {
#pragma unroll
      for (int k = 0; k < NKG; ++k) {
        u32x4 pk;
        pk[0] = (uint_t)f2b(pa[c][k][0]) | ((uint_t)f2b(pa[c][k][1]) << 16);
        pk[1] = (uint_t)f2b(pa[c][k][2]) | ((uint_t)f2b(pa[c][k][3]) << 16);
        pk[2] = (uint_t)f2b(pa[c][k][4]) | ((uint_t)f2b(pa[c][k][5]) << 16);
        pk[3] = (uint_t)f2b(pa[c][k][6]) | ((uint_t)f2b(pa[c][k][7]) << 16);
        *(u32x4*)(&lsA[c][spx * 40 + (kg0 + k * KGSTEP) * 8]) = pk;
      }
      if (bstage) *(u32x4*)(&lsB[c][sco * 40 + skg * 8]) = pb[c];
    }
    if (g + 1 < NGRP) loadgrp(g + 1);
    __syncthreads();
#pragma unroll
    for (int c = 0; c < GRP; ++c) {
      const short8 a0 = *(const short8*)(&lsA[c][(wm * 32 + arow) * 40 + ag * 8]);
      const short8 a1 = *(const short8*)(&lsA[c][(wm * 32 + 16 + arow) * 40 + ag * 8]);
      const short8 b0 = *(const short8*)(&lsB[c][(wn * 32 + arow) * 40 + ag * 8]);
      const short8 b1 = *(const short8*)(&lsB[c][(wn * 32 + 16 + arow) * 40 + ag * 8]);
      acc[0][0] = __builtin_amdgcn_mfma_f32_16x16x32_bf16(a0, b0, acc[0][0], 0, 0, 0);
      acc[0][1] = __builtin_amdgcn_mfma_f32_16x16x32_bf16(a0, b1, acc[0][1], 0, 0, 0);
      acc[1][0] = __builtin_amdgcn_mfma_f32_16x16x32_bf16(a1, b0, acc[1][0], 0, 0, 0);
      acc[1][1] = __builtin_amdgcn_mfma_f32_16x16x32_bf16(a1, b1, acc[1][1], 0, 0, 0);
    }
  }

  if constexpr (!FINAL) {
#pragma unroll
    for (int m = 0; m < 2; ++m)
#pragma unroll
      for (int n = 0; n < 2; ++n) {
        const int col = co_b0 + wn * 32 + n * 16 + arow;
        const float bv = bias[col];
        float* obase = out + (size_t)(b * COUT + col) * OUTSTRIDE;
#pragma unroll
        for (int r = 0; r < 4; ++r) {
          const int pxl = pxb0 + wm * 32 + m * 16 + ag * 4 + r;
          const int yy = pxl >> WSHIFT, xx = pxl & (W - 1);
          obase[(size_t)(2 * yy + ey + 1) * WOP + (2 * xx + ex + 1)] =
              fmaxf(acc[m][n][r] + bv, 0.0f);
        }
      }
  } else {
#pragma unroll
    for (int m = 0; m < 2; ++m)
#pragma unroll
      for (int n = 0; n < 2; ++n) {
        const int col = wn * 32 + n * 16 + arow;
        const float bv = bias[col];
#pragma unroll
        for (int r = 0; r < 4; ++r) {
          const int pxl = wm * 32 + m * 16 + ag * 4 + r;
          pxco[pxl][col] = fmaxf(acc[m][n][r] + bv, 0.0f);
        }
      }
    __syncthreads();
    if (tid < PXB) {
      const int pxg = pxb0 + tid;
      const int yy = pxg >> WSHIFT, xx = pxg & (W - 1);
      const int oy = 2 * yy + ey, ox = 2 * xx + ex;
      float o0 = ob[0], o1 = ob[1], o2 = ob[2];
#pragma unroll
      for (int co = 0; co < 32; ++co) {
        const float v = pxco[tid][co];
        o0 = fmaf(ow[co], v, o0);
        o1 = fmaf(ow[32 + co], v, o1);
        o2 = fmaf(ow[64 + co], v, o2);
      }
      out[((size_t)(b * 3 + 0) * 256 + oy) * 256 + ox] = o0;
      out[((size_t)(b * 3 + 1) * 256 + oy) * 256 + ox] = o1;
      out[((size_t)(b * 3 + 2) * 256 + oy) * 256 + ox] = o2;
    }
  }
}

// ---------------- VQ (fp32 exact) ----------------
__global__ __launch_bounds__(256) void k_vq(
    const float* __restrict__ zlat, const float* __restrict__ cbT,
    const float* __restrict__ cnorm, const float* __restrict__ cb,
    float* __restrict__ q, float* __restrict__ counts, float* __restrict__ sumsq) {
  const int tid = threadIdx.x;
  const int px0 = blockIdx.x << 4;
  const int b   = px0 >> 10;
  const int pl0 = px0 & 1023;
  __shared__ float zT[64][17];
  __shared__ float rd[16][256];
  __shared__ int   ri[16][256];
  for (int j = tid; j < 1024; j += 256) {
    const int ci = j >> 4, p = j & 15;
    zT[ci][p] = zlat[(size_t)(b * 64 + ci) * 1024 + pl0 + p];
  }
  __syncthreads();
  float dot[4][16];
#pragma unroll
  for (int k = 0; k < 4; ++k)
#pragma unroll
    for (int p = 0; p < 16; ++p) dot[k][p] = 0.0f;
  for (int ci = 0; ci < 64; ++ci) {
    float z[16];
#pragma unroll
    for (int p = 0; p < 16; ++p) z[p] = zT[ci][p];
#pragma unroll
    for (int k = 0; k < 4; ++k) {
      const float cv = cbT[(size_t)ci * 1024 + (k << 8) + tid];
#pragma unroll
      for (int p = 0; p < 16; ++p) dot[k][p] = fmaf(cv, z[p], dot[k][p]);
    }
  }
  float bd[16]; int bi[16];
#pragma unroll
  for (int p = 0; p < 16; ++p) { bd[p] = 3.4e38f; bi[p] = 0; }
#pragma unroll
  for (int k = 0; k < 4; ++k) {
    const int c = (k << 8) + tid;
    const float cn = cnorm[c];
#pragma unroll
    for (int p = 0; p < 16; ++p) {
      const float d = cn - 2.0f * dot[k][p];
      if (d < bd[p]) { bd[p] = d; bi[p] = c; }
    }
  }
#pragma unroll
  for (int p = 0; p < 16; ++p) { rd[p][tid] = bd[p]; ri[p][tid] = bi[p]; }
  __syncthreads();
  for (int s = 128; s >= 1; s >>= 1) {
    if (tid < s) {
#pragma unroll
      for (int p = 0; p < 16; ++p) {
        const float d2 = rd[p][tid + s]; const int i2 = ri[p][tid + s];
        const float d1 = rd[p][tid];     const int i1 = ri[p][tid];
        if (d2 < d1 || (d2 == d1 && i2 < i1)) { rd[p][tid] = d2; ri[p][tid] = i2; }
      }
    }
    __syncthreads();
  }
  if (tid < 16) atomicAdd(&counts[ri[tid][0]], 1.0f);
  const int p    = tid >> 4;
  const int best = ri[p][0];
  const int cb0  = (tid & 15) << 2;
  float ss = 0.0f;
  float* qp = q + (size_t)b * 65536 + pl0 + p;
#pragma unroll
  for (int cc = 0; cc < 4; ++cc) {
    const int ci = cb0 + cc;
    const float qv = cb[(size_t)best * 64 + ci];
    const float zv = zT[ci][p];
    const float df = qv - zv;
    ss += df * df;
    qp[(size_t)ci * 1024] = qv;
  }
#pragma unroll
  for (int o = 32; o > 0; o >>= 1) ss += __shfl_down(ss, o);
  if ((tid & 63) == 0) atomicAdd(sumsq, ss);
}

__global__ void k_final(const float* __restrict__ counts, const float* __restrict__ sumsq,
                        float* __restrict__ out2) {
  const int tid = threadIdx.x;
  float h = 0.0f;
  for (int k = tid; k < 1024; k += 256) {
    const float pr = counts[k] * (1.0f / 32768.0f);
    h -= pr * logf(pr + 1e-10f);
  }
#pragma unroll
  for (int o = 32; o > 0; o >>= 1) h += __shfl_down(h, o);
  __shared__ float hs[4];
  if ((tid & 63) == 0) hs[tid >> 6] = h;
  __syncthreads();
  if (tid == 0) {
    out2[0] = 1.25f * sumsq[0] * (1.0f / 2097152.0f);
    out2[1] = expf(hs[0] + hs[1] + hs[2] + hs[3]);
  }
}

// ---------------- launcher ----------------
extern "C" void kernel_launch(void* const* d_in, const int* in_sizes, int n_in,
                              void* d_out, int out_size, void* d_ws, size_t ws_size,
                              hipStream_t stream) {
  const float* x        = (const float*)d_in[0];
  const float* enc_w0   = (const float*)d_in[1];
  const float* enc_b0   = (const float*)d_in[2];
  const float* enc_w1   = (const float*)d_in[3];
  const float* enc_b1   = (const float*)d_in[4];
  const float* enc_w2   = (const float*)d_in[5];
  const float* enc_b2   = (const float*)d_in[6];
  const float* er0w1    = (const float*)d_in[7];
  const float* er0b1    = (const float*)d_in[8];
  const float* er0w2    = (const float*)d_in[9];
  const float* er0b2    = (const float*)d_in[10];
  const float* er1w1    = (const float*)d_in[11];
  const float* er1b1    = (const float*)d_in[12];
  const float* er1w2    = (const float*)d_in[13];
  const float* er1b2    = (const float*)d_in[14];
  const float* eadj_w   = (const float*)d_in[15];
  const float* eadj_b   = (const float*)d_in[16];
  const float* codebook = (const float*)d_in[17];
  const float* dadj_w   = (const float*)d_in[18];
  const float* dadj_b   = (const float*)d_in[19];
  const float* dr0w1    = (const float*)d_in[20];
  const float* dr0b1    = (const float*)d_in[21];
  const float* dr0w2    = (const float*)d_in[22];
  const float* dr0b2    = (const float*)d_in[23];
  const float* dr1w1    = (const float*)d_in[24];
  const float* dr1b1    = (const float*)d_in[25];
  const float* dr1w2    = (const float*)d_in[26];
  const float* dr1b2    = (const float*)d_in[27];
  const float* tw0      = (const float*)d_in[28];
  const float* tb0      = (const float*)d_in[29];
  const float* tw1      = (const float*)d_in[30];
  const float* tb1      = (const float*)d_in[31];
  const float* tw2      = (const float*)d_in[32];
  const float* tb2      = (const float*)d_in[33];
  const float* out_w    = (const float*)d_in[34];
  const float* out_b    = (const float*)d_in[35];

  float* ws = (float*)d_ws;
  float* A      = ws + A_OFF;
  float* Bb     = ws + B_OFF;
  float* C      = ws + C_OFF;
  float* Dq     = ws + D_OFF;
  float* E      = ws + E_OFF;
  float* Q      = ws + Q_OFF;
  float* cbT    = ws + CBT_OFF;
  float* cnorm  = ws + CNORM_OFF;
  float* counts = ws + COUNTS_OFF;
  float* sumsq  = ws + SUMSQ_OFF;

  size_t o = WT_OFF;
  float* wt_enc0  = ws + o; o += (size_t)3 * 16 * 64;
  float* wt_eadj  = ws + o; o += (size_t)256 * 64;
  float* wt_dadj  = ws + o; o += (size_t)64 * 256;
  // bf16 tconv weights
  ushort_t* wbT0 = (ushort_t*)(ws + o); o += 262144;  // 4*128*256*4 u16
  ushort_t* wbT1 = (ushort_t*)(ws + o); o += 65536;   // 4*64*128*4  u16
  ushort_t* wbT2 = (ushort_t*)(ws + o); o += 16384;   // 4*32*64*4   u16
  // split bf16 encoder conv weights
  ushort_t* wsh1 = (ushort_t*)(ws + o); o += 65536;   // 128*64*16 u16
  ushort_t* wsl1 = (ushort_t*)(ws + o); o += 65536;
  ushort_t* wsh2 = (ushort_t*)(ws + o); o += 262144;  // 256*128*16 u16
  ushort_t* wsl2 = (ushort_t*)(ws + o); o += 262144;
  // split bf16 conv3x3 weights [9t][64co][256ci]
  ushort_t* w3h_er0 = (ushort_t*)(ws + o); o += 73728;
  ushort_t* w3l_er0 = (ushort_t*)(ws + o); o += 73728;
  ushort_t* w3h_er1 = (ushort_t*)(ws + o); o += 73728;
  ushort_t* w3l_er1 = (ushort_t*)(ws + o); o += 73728;
  ushort_t* w3h_dr0 = (ushort_t*)(ws + o); o += 73728;
  ushort_t* w3l_dr0 = (ushort_t*)(ws + o); o += 73728;
  ushort_t* w3h_dr1 = (ushort_t*)(ws + o); o += 73728;
  ushort_t* w3l_dr1 = (ushort_t*)(ws + o); o += 73728;
  // split bf16 res 1x1 weights [256co][64ci]
  ushort_t* w2h_er0 = (ushort_t*)(ws + o); o += 8192;
  ushort_t* w2l_er0 = (ushort_t*)(ws + o); o += 8192;
  ushort_t* w2h_er1 = (ushort_t*)(ws + o); o += 8192;
  ushort_t* w2l_er1 = (ushort_t*)(ws + o); o += 8192;
  ushort_t* w2h_dr0 = (ushort_t*)(ws + o); o += 8192;
  ushort_t* w2l_dr0 = (ushort_t*)(ws + o); o += 8192;
  ushort_t* w2h_dr1 = (ushort_t*)(ws + o); o += 8192;
  ushort_t* w2l_dr1 = (ushort_t*)(ws + o); o += 8192;

  float* fout = (float*)d_out;

  #define GB(n) (((n) + 255) / 256)
  // targeted zeroing: counters + halos of A, Bb
  k_zero<<<4, 256, 0, stream>>>(counts, sumsq);
  k_halo<<<2048, 64, 0, stream>>>(A, 130, 130);
  k_halo<<<4096, 64, 0, stream>>>(Bb, 66, 66);

  // consolidated weight prep (5 dispatches instead of 17)
  k_wt_conv_multi<<<dim3(64, 3), 256, 0, stream>>>(enc_w0, wt_enc0, eadj_w, wt_eadj,
                                                   dadj_w, wt_dadj);
  k_wtb_multi<<<dim3(2048, 3), 256, 0, stream>>>(tw0, wbT0, tw1, wbT1, tw2, wbT2);
  k_wsplit_enc<<<dim3(2048, 2), 256, 0, stream>>>(enc_w1, wsh1, wsl1, enc_w2, wsh2, wsl2);
  k_wsplit_w2m<<<dim3(64, 4), 256, 0, stream>>>(er0w2, w2h_er0, w2l_er0,
                                                er1w2, w2h_er1, w2l_er1,
                                                dr0w2, w2h_dr0, w2l_dr0,
                                                dr1w2, w2h_dr1, w2l_dr1);
  k_wt3split_multi<<<dim3(576, 4), 256, 0, stream>>>(er0w1, w3h_er0, w3l_er0,
                                                     er1w1, w3h_er1, w3l_er1,
                                                     dr0w1, w3h_dr0, w3l_dr0,
                                                     dr1w1, w3h_dr1, w3l_dr1);
  k_cbt<<<4, 256, 0, stream>>>(codebook, cbT, cnorm);

  // ---------- encoder (split-bf16 MFMA ~ fp32 accuracy; protects VQ argmin) ----------
  k_conv4s2_s3<<<dim3(16, 4, 32), 256, 0, stream>>>(x, wt_enc0, enc_b0, A);
  k_conv4s2_mfma<6, 64, 128, 130, 16900, 66, 4356>
      <<<dim3(64, 2, 32), 256, 0, stream>>>(A, wsh1, wsl1, enc_b1, Bb);
  // A now dead -> zero C/Dq halos
  k_halo<<<8192, 64, 0, stream>>>(C, 34, 34);
  k_halo<<<8192, 64, 0, stream>>>(Dq, 34, 34);
  k_conv4s2_mfma<5, 128, 256, 66, 4356, 34, 1156>
      <<<dim3(16, 4, 32), 256, 0, stream>>>(Bb, wsh2, wsl2, enc_b2, C);
  k_res_mfma<<<dim3(16, 1, 32), 512, 0, stream>>>(C, w3h_er0, w3l_er0, er0b1,
                                                  w2h_er0, w2l_er0, er0b2, Dq);
  k_res_mfma<<<dim3(16, 1, 32), 512, 0, stream>>>(Dq, w3h_er1, w3l_er1, er1b1,
                                                  w2h_er1, w2l_er1, er1b2, C);
  k_conv1x1_px<0, 0, 1, 0><<<dim3(4, 4, 32), 256, 0, stream>>>(C, wt_eadj, eadj_b, nullptr, E, 256, 64);
  // ---------- VQ (fp32 exact) ----------
  k_vq<<<2048, 256, 0, stream>>>(E, cbT, cnorm, codebook, Q, counts, sumsq);
  // ---------- decoder ----------
  k_conv1x1_px<0, 0, 0, 1><<<dim3(4, 16, 32), 256, 0, stream>>>(Q, wt_dadj, dadj_b, nullptr, C, 64, 256);
  k_res_mfma<<<dim3(16, 1, 32), 512, 0, stream>>>(C, w3h_dr0, w3l_dr0, dr0b1,
                                                  w2h_dr0, w2l_dr0, dr0b2, Dq);
  k_res_mfma<<<dim3(16, 1, 32), 512, 0, stream>>>(Dq, w3h_dr1, w3l_dr1, dr1b1,
                                                  w2h_dr1, w2l_dr1, dr1b2, C);
  // MFMA bf16 transposed convs
  k_tconv_mfma<64, 64, 5, 256, 128, 34, 1156, 66, 4356, 0, 2>
      <<<dim3(16, 8, 32), 256, 0, stream>>>(C, wbT0, tb0, nullptr, nullptr, Bb);
  // C/D/E/Q dead -> re-zero A halos
  k_halo<<<2048, 64, 0, stream>>>(A, 130, 130);
  k_tconv_mfma<64, 64, 6, 128, 64, 66, 4356, 130, 16900, 0, 2>
      <<<dim3(64, 4, 32), 256, 0, stream>>>(Bb, wbT1, tb1, nullptr, nullptr, A);
  k_tconv_mfma<128, 32, 7, 64, 32, 130, 16900, 0, 0, 1, 1>
      <<<dim3(128, 4, 32), 256, 0, stream>>>(A, wbT2, tb2, out_w, out_b, fout);
  k_final<<<1, 256, 0, stream>>>(counts, sumsq, fout + 6291456);
  #undef GB
}

// Round 17
// 1638.582 us; speedup vs baseline: 1.0819x; 1.0185x over previous
//
#include <hip/hip_runtime.h>
#include <math.h>

typedef __attribute__((ext_vector_type(4))) float f32x4;
typedef __attribute__((ext_vector_type(8))) short short8;
typedef __attribute__((ext_vector_type(4))) unsigned int u32x4;
typedef unsigned short ushort_t;
typedef unsigned int uint_t;

// ---------------- workspace layout (float offsets), lifetime-packed, PADDED activations ----
static const size_t A_OFF      = 0;
static const size_t C_OFF      = 0;
static const size_t D_OFF      = 9469952;
static const size_t E_OFF      = 18939904;
static const size_t Q_OFF      = 21037056;
static const size_t B_OFF      = 34611200;
static const size_t CBT_OFF    = 52453376;  // 64*1024
static const size_t CNORM_OFF  = 52518912;  // 1024
static const size_t COUNTS_OFF = 52519936;  // 1024
static const size_t SUMSQ_OFF  = 52520960;  // 1 (+3)
static const size_t WT_OFF     = 52520964;  // transposed weights + bf16/split weights

__device__ __forceinline__ ushort_t f2b(float f) {
  uint_t u = __float_as_uint(f);
  uint_t r = (u + 0x7FFFu + ((u >> 16) & 1u)) >> 16;
  return (ushort_t)r;
}
__device__ __forceinline__ float b2f(ushort_t h) {
  return __uint_as_float(((uint_t)h) << 16);
}
__device__ __forceinline__ uint_t pk2(ushort_t a, ushort_t c) {
  return (uint_t)a | ((uint_t)c << 16);
}

// ---------------- utility: zero pad ring of one padded plane ----------------
__global__ void k_halo(float* __restrict__ buf, int HP, int WP) {
  const int plane = blockIdx.x;
  float* p = buf + (size_t)plane * HP * WP;
  const int ring = 2 * (HP + WP) - 4;
  for (int i = threadIdx.x; i < ring; i += blockDim.x) {
    int idx;
    if (i < WP) idx = i;
    else if (i < 2 * WP) idx = (HP - 1) * WP + (i - WP);
    else {
      const int j = i - 2 * WP;
      const int r = 1 + (j >> 1);
      idx = r * WP + ((j & 1) ? (WP - 1) : 0);
    }
    p[idx] = 0.0f;
  }
}
__global__ void k_halo_h(ushort_t* __restrict__ buf, int HP, int WP) {
  const int plane = blockIdx.x;
  ushort_t* p = buf + (size_t)plane * HP * WP;
  const int ring = 2 * (HP + WP) - 4;
  for (int i = threadIdx.x; i < ring; i += blockDim.x) {
    int idx;
    if (i < WP) idx = i;
    else if (i < 2 * WP) idx = (HP - 1) * WP + (i - WP);
    else {
      const int j = i - 2 * WP;
      const int r = 1 + (j >> 1);
      idx = r * WP + ((j & 1) ? (WP - 1) : 0);
    }
    p[idx] = (ushort_t)0;
  }
}
__global__ void k_zero(float* __restrict__ counts, float* __restrict__ sumsq) {
  const int t = blockIdx.x * 256 + threadIdx.x;
  if (t < 1024) counts[t] = 0.0f;
  if (t == 0) sumsq[0] = 0.0f;
}

// ---------------- weight prep (batched multi-tensor kernels) ----------------
__device__ __forceinline__ void wt_conv_body(const float* w, float* wT,
                                             int Cin, int Cout, int K) {
  const int n = Cin * Cout * K;
  for (int i = blockIdx.x * 256 + threadIdx.x; i < n; i += gridDim.x * 256) {
    const int co = i % Cout;
    const int k  = (i / Cout) % K;
    const int ci = i / (Cout * K);
    wT[i] = w[((size_t)co * Cin + ci) * K + k];
  }
}
__global__ void k_wt_conv_multi(const float* w0, float* o0, const float* w1, float* o1,
                                const float* w2, float* o2) {
  if (blockIdx.y == 0) wt_conv_body(w0, o0, 3, 64, 16);
  else if (blockIdx.y == 1) wt_conv_body(w1, o1, 256, 64, 1);
  else wt_conv_body(w2, o2, 64, 256, 1);
}
__device__ __forceinline__ void wtb_body(const float* w, ushort_t* wbT,
                                         int Cin, int Cout) {
  const int n = 4 * Cout * Cin * 4;
  for (int i = blockIdx.x * 256 + threadIdx.x; i < n; i += gridDim.x * 256) {
    const int tap = i & 3;
    const int ci  = (i >> 2) % Cin;
    const int co  = ((i >> 2) / Cin) % Cout;
    const int ph  = (i >> 2) / (Cin * Cout);
    const int ey = ph >> 1, ex = ph & 1;
    const int ty = tap >> 1, tx = tap & 1;
    const int kidx = (3 - 2 * ty - ey) * 4 + (3 - 2 * tx - ex);
    wbT[i] = f2b(w[((size_t)ci * Cout + co) * 16 + kidx]);
  }
}
__global__ void k_wtb_multi(const float* t0, ushort_t* o0, const float* t1, ushort_t* o1,
                            const float* t2, ushort_t* o2) {
  if (blockIdx.y == 0) wtb_body(t0, o0, 256, 128);
  else if (blockIdx.y == 1) wtb_body(t1, o1, 128, 64);
  else wtb_body(t2, o2, 64, 32);
}
__device__ __forceinline__ void wsplit_body(const float* w, ushort_t* wh,
                                            ushort_t* wl, int n) {
  for (int i = blockIdx.x * 256 + threadIdx.x; i < n; i += gridDim.x * 256) {
    const float v = w[i];
    const ushort_t h = f2b(v);
    wh[i] = h;
    wl[i] = f2b(v - b2f(h));
  }
}
__global__ void k_wsplit_enc(const float* w1, ushort_t* h1, ushort_t* l1,
                             const float* w2, ushort_t* h2, ushort_t* l2) {
  if (blockIdx.y == 0) wsplit_body(w1, h1, l1, 131072);
  else wsplit_body(w2, h2, l2, 524288);
}
__global__ void k_wsplit_w2m(const float* a, ushort_t* ah, ushort_t* al,
                             const float* b, ushort_t* bh, ushort_t* bl,
                             const float* c, ushort_t* ch, ushort_t* cl,
                             const float* d, ushort_t* dh, ushort_t* dl) {
  if (blockIdx.y == 0) wsplit_body(a, ah, al, 16384);
  else if (blockIdx.y == 1) wsplit_body(b, bh, bl, 16384);
  else if (blockIdx.y == 2) wsplit_body(c, ch, cl, 16384);
  else wsplit_body(d, dh, dl, 16384);
}
__device__ __forceinline__ void wt3_body(const float* w, ushort_t* wh, ushort_t* wl) {
  const int n = 9 * 64 * 256;
  for (int i = blockIdx.x * 256 + threadIdx.x; i < n; i += gridDim.x * 256) {
    const int ci = i & 255;
    const int co = (i >> 8) & 63;
    const int t  = i >> 14;
    const float v = w[((size_t)co * 256 + ci) * 9 + t];
    const ushort_t h = f2b(v);
    wh[i] = h;
    wl[i] = f2b(v - b2f(h));
  }
}
__global__ void k_wt3split_multi(const float* a, ushort_t* ah, ushort_t* al,
                                 const float* b, ushort_t* bh, ushort_t* bl,
                                 const float* c, ushort_t* ch, ushort_t* cl,
                                 const float* d, ushort_t* dh, ushort_t* dl) {
  if (blockIdx.y == 0) wt3_body(a, ah, al);
  else if (blockIdx.y == 1) wt3_body(b, bh, bl);
  else if (blockIdx.y == 2) wt3_body(c, ch, cl);
  else wt3_body(d, dh, dl);
}
// codebook [1024,64] -> cbT [64][1024] + cnorm[1024]
__global__ void k_cbt(const float* __restrict__ cb, float* __restrict__ cbT,
                      float* __restrict__ cnorm) {
  const int c = blockIdx.x * 256 + threadIdx.x;
  float s = 0.0f;
  for (int ci = 0; ci < 64; ++ci) {
    const float v = cb[(size_t)c * 64 + ci];
    s += v * v;
    cbT[(size_t)ci * 1024 + c] = v;
  }
  cnorm[c] = s;
}

// ---------------- enc0: conv 4x4 s2 p1, Cin=3, staged, PADDED fp32 out ----------
__global__ __launch_bounds__(256) void k_conv4s2_s3(
    const float* __restrict__ in, const float* __restrict__ wT,
    const float* __restrict__ bias, float* __restrict__ out) {
  const int b   = blockIdx.z;
  const int co0 = blockIdx.y << 4;
  const int oy0 = (blockIdx.x >> 2) << 5;
  const int ox0 = (blockIdx.x & 3) << 5;
  const int tid = threadIdx.x;
  const int ty = tid >> 4, tx = tid & 15;
  __shared__ float tin[3][66][67];
  float acc[4][16];
#pragma unroll
  for (int p = 0; p < 4; ++p)
#pragma unroll
    for (int co = 0; co < 16; ++co) acc[p][co] = 0.0f;

  const int iy0 = (oy0 << 1) - 1, ix0 = (ox0 << 1) - 1;
  for (int c = 0; c < 3; ++c) {
    const float* ip = in + (size_t)(b * 3 + c) * 65536;
    for (int j = tid; j < 66 * 66; j += 256) {
      const int r = j / 66, col = j - r * 66;
      const int iy = iy0 + r, ix = ix0 + col;
      float v = 0.0f;
      if ((unsigned)iy < 256u && (unsigned)ix < 256u) v = ip[iy * 256 + ix];
      tin[c][r][col] = v;
    }
  }
  __syncthreads();
#pragma unroll
  for (int c = 0; c < 3; ++c) {
    const float* wp = wT + (size_t)c * 16 * 64 + co0;
#pragma unroll
    for (int ky = 0; ky < 4; ++ky)
#pragma unroll
      for (int kx = 0; kx < 4; ++kx) {
        const float v0 = tin[c][2 * ty + ky][2 * tx + kx];
        const float v1 = tin[c][2 * ty + ky][2 * tx + 32 + kx];
        const float v2 = tin[c][2 * ty + 32 + ky][2 * tx + kx];
        const float v3 = tin[c][2 * ty + 32 + ky][2 * tx + 32 + kx];
        const float* wk = wp + (ky * 4 + kx) * 64;
#pragma unroll
        for (int co = 0; co < 16; ++co) {
          const float wv = wk[co];
          acc[0][co] = fmaf(v0, wv, acc[0][co]);
          acc[1][co] = fmaf(v1, wv, acc[1][co]);
          acc[2][co] = fmaf(v2, wv, acc[2][co]);
          acc[3][co] = fmaf(v3, wv, acc[3][co]);
        }
      }
  }
#pragma unroll
  for (int co = 0; co < 16; ++co) {
    const float bv = bias[co0 + co];
    float* op = out + (size_t)(b * 64 + co0 + co) * 16900;
    op[(size_t)(oy0 + ty + 1) * 130 + ox0 + tx + 1]        = fmaxf(acc[0][co] + bv, 0.0f);
    op[(size_t)(oy0 + ty + 1) * 130 + ox0 + tx + 17]       = fmaxf(acc[1][co] + bv, 0.0f);
    op[(size_t)(oy0 + ty + 17) * 130 + ox0 + tx + 1]       = fmaxf(acc[2][co] + bv, 0.0f);
    op[(size_t)(oy0 + ty + 17) * 130 + ox0 + tx + 17]      = fmaxf(acc[3][co] + bv, 0.0f);
  }
}

// ---------------- split-bf16 MFMA conv 4x4 s2 p1 (encoder; ~fp32 accuracy) ----------------
template <int WSHIFT, int CIN, int COUT, int WP, int INSTRIDE, int WOP, int OUTSTRIDE>
__global__ __launch_bounds__(256) void k_conv4s2_mfma(
    const float* __restrict__ in, const ushort_t* __restrict__ wbh,
    const ushort_t* __restrict__ wbl, const float* __restrict__ bias,
    float* __restrict__ out) {
  constexpr int W = 1 << WSHIFT;
  constexpr int NCH = CIN / 2;  // K-chunk = 32 = 2 ci x 16 taps
  __shared__ __align__(16) short lsAh[64 * 40];
  __shared__ __align__(16) short lsAl[64 * 40];
  __shared__ __align__(16) short lsBh[64 * 40];
  __shared__ __align__(16) short lsBl[64 * 40];

  const int tid = threadIdx.x;
  const int b = blockIdx.z;
  const int co_b0 = blockIdx.y << 6;
  const int pxb0 = blockIdx.x << 6;

  const int spx = tid & 63;
  const int kg  = tid >> 6;
  const int sy = (pxb0 + spx) >> WSHIFT;
  const int sx = (pxb0 + spx) & (W - 1);
  const float* ipa = in + (size_t)(b * CIN + (kg >> 1)) * INSTRIDE
                   + (size_t)(2 * sy + 2 * (kg & 1)) * WP + 2 * sx;
  const ushort_t* wbase_h = wbh + (size_t)(co_b0 + spx) * (CIN * 16) + kg * 8;
  const ushort_t* wbase_l = wbl + (size_t)(co_b0 + spx) * (CIN * 16) + kg * 8;

  const int lane = tid & 63, wid = tid >> 6;
  const int wm = wid & 1, wn = wid >> 1;
  const int arow = lane & 15, ag = lane >> 4;

  f32x4 acc[2][2];
#pragma unroll
  for (int m = 0; m < 2; ++m)
#pragma unroll
    for (int n = 0; n < 2; ++n) acc[m][n] = (f32x4){0.f, 0.f, 0.f, 0.f};

  float pa[8];
  u32x4 pbh, pbl;
  auto loadch = [&](int ch) {
    const float* p = ipa + (size_t)ch * 2 * INSTRIDE;
    pa[0] = p[0];  pa[1] = p[1];      pa[2] = p[2];      pa[3] = p[3];
    pa[4] = p[WP]; pa[5] = p[WP + 1]; pa[6] = p[WP + 2]; pa[7] = p[WP + 3];
    pbh = *(const u32x4*)(wbase_h + (size_t)ch * 32);
    pbl = *(const u32x4*)(wbase_l + (size_t)ch * 32);
  };

  loadch(0);
  for (int ch = 0; ch < NCH; ++ch) {
    __syncthreads();
    u32x4 vh, vl;
#pragma unroll
    for (int j = 0; j < 4; ++j) {
      const ushort_t h0 = f2b(pa[2 * j]);
      const ushort_t h1 = f2b(pa[2 * j + 1]);
      const ushort_t l0 = f2b(pa[2 * j] - b2f(h0));
      const ushort_t l1 = f2b(pa[2 * j + 1] - b2f(h1));
      vh[j] = (uint_t)h0 | ((uint_t)h1 << 16);
      vl[j] = (uint_t)l0 | ((uint_t)l1 << 16);
    }
    *(u32x4*)(&lsAh[spx * 40 + kg * 8]) = vh;
    *(u32x4*)(&lsAl[spx * 40 + kg * 8]) = vl;
    *(u32x4*)(&lsBh[spx * 40 + kg * 8]) = pbh;
    *(u32x4*)(&lsBl[spx * 40 + kg * 8]) = pbl;
    if (ch + 1 < NCH) loadch(ch + 1);
    __syncthreads();
    short8 ah[2], al[2], bh[2], bl[2];
#pragma unroll
    for (int m = 0; m < 2; ++m) {
      ah[m] = *(const short8*)(&lsAh[(wm * 32 + m * 16 + arow) * 40 + ag * 8]);
      al[m] = *(const short8*)(&lsAl[(wm * 32 + m * 16 + arow) * 40 + ag * 8]);
    }
#pragma unroll
    for (int n = 0; n < 2; ++n) {
      bh[n] = *(const short8*)(&lsBh[(wn * 32 + n * 16 + arow) * 40 + ag * 8]);
      bl[n] = *(const short8*)(&lsBl[(wn * 32 + n * 16 + arow) * 40 + ag * 8]);
    }
#pragma unroll
    for (int m = 0; m < 2; ++m)
#pragma unroll
      for (int n = 0; n < 2; ++n) {
        acc[m][n] = __builtin_amdgcn_mfma_f32_16x16x32_bf16(ah[m], bh[n], acc[m][n], 0, 0, 0);
        acc[m][n] = __builtin_amdgcn_mfma_f32_16x16x32_bf16(ah[m], bl[n], acc[m][n], 0, 0, 0);
        acc[m][n] = __builtin_amdgcn_mfma_f32_16x16x32_bf16(al[m], bh[n], acc[m][n], 0, 0, 0);
      }
  }

#pragma unroll
  for (int m = 0; m < 2; ++m)
#pragma unroll
    for (int n = 0; n < 2; ++n) {
      const int col = co_b0 + wn * 32 + n * 16 + arow;
      const float bv = bias[col];
      float* obase = out + (size_t)(b * COUT + col) * OUTSTRIDE;
#pragma unroll
      for (int r = 0; r < 4; ++r) {
        const int pxl = pxb0 + wm * 32 + m * 16 + ag * 4 + r;
        const int yy = pxl >> WSHIFT, xx = pxl & (W - 1);
        obase[(size_t)(yy + 1) * WOP + (xx + 1)] = fmaxf(acc[m][n][r] + bv, 0.0f);
      }
    }
}

// ---------------- FUSED res-block: conv3x3(relu(x)) -> relu -> 1x1 -> +x  ----------
// OUTB: 0 = fp32 padded plane, 1 = bf16 (u16) padded plane.
template <int OUTB>
__global__ __launch_bounds__(512) void k_res_mfma(
    const float* __restrict__ in, const ushort_t* __restrict__ w3h,
    const ushort_t* __restrict__ w3l, const float* __restrict__ b1,
    const ushort_t* __restrict__ w2h, const ushort_t* __restrict__ w2l,
    const float* __restrict__ b2, float* __restrict__ out) {
  __shared__ __align__(16) short smem[10240];
  short* lsAh = smem;
  short* lsAl = smem + 2560;
  short* lsBh = smem + 5120;
  short* lsBl = smem + 7680;

  const int tid = threadIdx.x;
  const int b = blockIdx.z;
  const int pxb0 = blockIdx.x << 6;
  const bool isA = tid < 256;
  const int sidx = tid & 63;
  const int skg  = (tid >> 6) & 3;

  const int py = (pxb0 + sidx) >> 5;
  const int pxx = (pxb0 + sidx) & 31;
  const float* ipa = in + (size_t)b * 256 * 1156 + (size_t)py * 34 + pxx;

  const int lane = tid & 63, wid = tid >> 6;
  const int wm = wid & 1, wn = wid >> 1;
  const int arow = lane & 15, ag = lane >> 4;

  f32x4 acc[2];
  acc[0] = (f32x4){0.f, 0.f, 0.f, 0.f};
  acc[1] = (f32x4){0.f, 0.f, 0.f, 0.f};

  float pa[8];
  u32x4 pbh, pbl;
  auto loadit = [&](int it) {
    const int t = it >> 3, ck = it & 7;
    if (isA) {
      const int dy = t / 3, dx = t - 3 * (t / 3);
      const float* p = ipa + (size_t)(ck * 32 + skg * 8) * 1156 + dy * 34 + dx;
#pragma unroll
      for (int j = 0; j < 8; ++j) pa[j] = p[(size_t)j * 1156];
    } else {
      const ushort_t* ph = w3h + ((size_t)(t * 64 + sidx) << 8) + ck * 32 + skg * 8;
      const ushort_t* pl = w3l + ((size_t)(t * 64 + sidx) << 8) + ck * 32 + skg * 8;
      pbh = *(const u32x4*)ph;
      pbl = *(const u32x4*)pl;
    }
  };

  loadit(0);
  for (int it = 0; it < 72; ++it) {
    __syncthreads();
    if (isA) {
      u32x4 vh, vl;
#pragma unroll
      for (int j = 0; j < 4; ++j) {
        const float v0 = fmaxf(pa[2 * j], 0.0f);
        const float v1 = fmaxf(pa[2 * j + 1], 0.0f);
        const ushort_t h0 = f2b(v0);
        const ushort_t h1 = f2b(v1);
        const ushort_t l0 = f2b(v0 - b2f(h0));
        const ushort_t l1 = f2b(v1 - b2f(h1));
        vh[j] = (uint_t)h0 | ((uint_t)h1 << 16);
        vl[j] = (uint_t)l0 | ((uint_t)l1 << 16);
      }
      *(u32x4*)(&lsAh[sidx * 40 + skg * 8]) = vh;
      *(u32x4*)(&lsAl[sidx * 40 + skg * 8]) = vl;
    } else {
      *(u32x4*)(&lsBh[sidx * 40 + skg * 8]) = pbh;
      *(u32x4*)(&lsBl[sidx * 40 + skg * 8]) = pbl;
    }
    if (it + 1 < 72) loadit(it + 1);
    __syncthreads();
    short8 ah[2], al[2];
#pragma unroll
    for (int m = 0; m < 2; ++m) {
      ah[m] = *(const short8*)(&lsAh[(wm * 32 + m * 16 + arow) * 40 + ag * 8]);
      al[m] = *(const short8*)(&lsAl[(wm * 32 + m * 16 + arow) * 40 + ag * 8]);
    }
    const short8 bh = *(const short8*)(&lsBh[(wn * 16 + arow) * 40 + ag * 8]);
    const short8 bl = *(const short8*)(&lsBl[(wn * 16 + arow) * 40 + ag * 8]);
#pragma unroll
    for (int m = 0; m < 2; ++m) {
      acc[m] = __builtin_amdgcn_mfma_f32_16x16x32_bf16(ah[m], bh, acc[m], 0, 0, 0);
      acc[m] = __builtin_amdgcn_mfma_f32_16x16x32_bf16(ah[m], bl, acc[m], 0, 0, 0);
      acc[m] = __builtin_amdgcn_mfma_f32_16x16x32_bf16(al[m], bh, acc[m], 0, 0, 0);
    }
  }

  // ---- store relu(h + b1) as split bf16 into smem [64px][72] (hi @0, lo @4608) ----
  __syncthreads();
  {
    const float bv = b1[wn * 16 + arow];
    short* hh = smem;
    short* hl = smem + 4608;
#pragma unroll
    for (int m = 0; m < 2; ++m)
#pragma unroll
      for (int r = 0; r < 4; ++r) {
        const int pxl = wm * 32 + m * 16 + ag * 4 + r;
        const float v = fmaxf(acc[m][r] + bv, 0.0f);
        const ushort_t h = f2b(v);
        hh[pxl * 72 + wn * 16 + arow] = (short)h;
        hl[pxl * 72 + wn * 16 + arow] = (short)f2b(v - b2f(h));
      }
  }
  __syncthreads();

  // ---- GEMM2: M=64px N=256co K=64, pipelined (prefetch B_{j+1}, resid_j, bias_j) ----
  const int m2 = wid & 3;
  const int nh = wid >> 2;
  const short* hh = smem;
  const short* hl = smem + 4608;
  short8 a2h[2], a2l[2];
#pragma unroll
  for (int c = 0; c < 2; ++c) {
    a2h[c] = *(const short8*)(&hh[(m2 * 16 + arow) * 72 + c * 32 + ag * 8]);
    a2l[c] = *(const short8*)(&hl[(m2 * 16 + arow) * 72 + c * 32 + ag * 8]);
  }
  const int px0 = pxb0 + m2 * 16 + ag * 4;
  const int yy0 = px0 >> 5, xx0 = px0 & 31;
  const int ridx = (yy0 + 1) * 34 + xx0 + 1;

  short8 cbh[2], cbl[2], nbh[2], nbl[2];
  float rv[4], nrv[4], bvc, nbvc;
  auto loadj = [&](int j, short8* oh, short8* ol, float* rr, float* bb) {
    const int col2 = (nh * 8 + j) * 16 + arow;
#pragma unroll
    for (int c = 0; c < 2; ++c) {
      oh[c] = *(const short8*)(w2h + (size_t)col2 * 64 + c * 32 + ag * 8);
      ol[c] = *(const short8*)(w2l + (size_t)col2 * 64 + c * 32 + ag * 8);
    }
    const float* rbase = in + (size_t)(b * 256 + col2) * 1156 + ridx;
#pragma unroll
    for (int r = 0; r < 4; ++r) rr[r] = rbase[r];
    *bb = b2[col2];
  };

  loadj(0, cbh, cbl, rv, &bvc);
#pragma unroll
  for (int j = 0; j < 8; ++j) {
    if (j + 1 < 8) loadj(j + 1, nbh, nbl, nrv, &nbvc);
    f32x4 acc2 = (f32x4){0.f, 0.f, 0.f, 0.f};
#pragma unroll
    for (int c = 0; c < 2; ++c) {
      acc2 = __builtin_amdgcn_mfma_f32_16x16x32_bf16(a2h[c], cbh[c], acc2, 0, 0, 0);
      acc2 = __builtin_amdgcn_mfma_f32_16x16x32_bf16(a2h[c], cbl[c], acc2, 0, 0, 0);
      acc2 = __builtin_amdgcn_mfma_f32_16x16x32_bf16(a2l[c], cbh[c], acc2, 0, 0, 0);
    }
    const int col2 = (nh * 8 + j) * 16 + arow;
    if constexpr (OUTB) {
      ushort_t* ob16 = (ushort_t*)out + (size_t)(b * 256 + col2) * 1156 + ridx;
#pragma unroll
      for (int r = 0; r < 4; ++r) ob16[r] = f2b(acc2[r] + bvc + rv[r]);
    } else {
      float* obase = out + (size_t)(b * 256 + col2) * 1156 + ridx;
#pragma unroll
      for (int r = 0; r < 4; ++r) obase[r] = acc2[r] + bvc + rv[r];
    }
#pragma unroll
    for (int c = 0; c < 2; ++c) { cbh[c] = nbh[c]; cbl[c] = nbl[c]; }
#pragma unroll
    for (int r = 0; r < 4; ++r) rv[r] = nrv[r];
    bvc = nbvc;
  }
}

// ---------------- conv1x1 px-parallel; pad-aware in/out ----------
template <int IN_RELU, int HAS_RES, int IN_PAD, int OUT_PAD>
__global__ __launch_bounds__(256) void k_conv1x1_px(
    const float* __restrict__ in, const float* __restrict__ wT,
    const float* __restrict__ bias, const float* __restrict__ res,
    float* __restrict__ out, int Cin, int Cout) {
  const int b   = blockIdx.z;
  const int co0 = blockIdx.y << 4;
  const int px  = blockIdx.x * 256 + threadIdx.x;
  const int ppad = 35 + px + 2 * (px >> 5);
  const int ioff = IN_PAD ? ppad : px;
  const int istr = IN_PAD ? 1156 : 1024;
  const int ooff = OUT_PAD ? ppad : px;
  const int ostr = OUT_PAD ? 1156 : 1024;
  float acc[16];
#pragma unroll
  for (int co = 0; co < 16; ++co) acc[co] = 0.0f;
  const float* ip = in + (size_t)b * Cin * istr + ioff;
  const float* wp = wT + co0;
  for (int ci = 0; ci < Cin; ++ci) {
    float v = *ip;
    if (IN_RELU) v = fmaxf(v, 0.0f);
    ip += istr;
#pragma unroll
    for (int co = 0; co < 16; ++co) acc[co] = fmaf(v, wp[co], acc[co]);
    wp += Cout;
  }
  float* op = out + (size_t)(b * Cout + co0) * ostr + ooff;
  const float* rp = res + (size_t)(b * Cout + co0) * ostr + ooff;
#pragma unroll
  for (int co = 0; co < 16; ++co) {
    float r = acc[co] + bias[co0 + co];
    if (HAS_RES) r += rp[(size_t)co * ostr];
    op[(size_t)co * ostr] = r;
  }
}

// ---------------- MFMA bf16 tconv, reg-prefetch, GRP chunks; INB/OUTB bf16 planes ---------
template <int PXB, int COB, int WSHIFT, int CIN, int COUT, int WP,
          int INSTRIDE, int WOP, int OUTSTRIDE, int FINAL, int GRP, int INB, int OUTB>
__global__ __launch_bounds__(256) void k_tconv_mfma(
    const void* __restrict__ in_, const ushort_t* __restrict__ wbT,
    const float* __restrict__ bias, const float* __restrict__ ow,
    const float* __restrict__ ob, void* __restrict__ out_) {
  constexpr int W = 1 << WSHIFT;
  constexpr int NCH = CIN / 8;
  constexpr int NGRP = NCH / GRP;
  constexpr int PXSH = (PXB == 64) ? 6 : 7;
  constexpr int COSH = (COB == 64) ? 6 : 5;
  constexpr int NKG = (PXB * 4) / 256;
  constexpr int KGSTEP = 256 / PXB;
  __shared__ __align__(16) short lsA[GRP][PXB * 40];
  __shared__ __align__(16) short lsB[GRP][COB * 40];
  __shared__ float pxco[FINAL ? PXB : 1][33];

  const int tid = threadIdx.x;
  const int b = blockIdx.z;
  const int phase = blockIdx.y & 3;
  const int ey = phase >> 1, ex = phase & 1;
  const int co_b0 = (blockIdx.y >> 2) * COB;
  const int pxb0 = blockIdx.x * PXB;

  const int spx = tid & (PXB - 1);
  const int kg0 = tid >> PXSH;
  const int sy = (pxb0 + spx) >> WSHIFT;
  const int sx = (pxb0 + spx) & (W - 1);
  const size_t abase = (size_t)b * CIN * INSTRIDE + (size_t)(sy + ey) * WP + (sx + ex);
  const int sco = tid & (COB - 1);
  const int skg = tid >> COSH;
  const bool bstage = (tid < COB * 4);
  const ushort_t* wrow = wbT + ((size_t)(phase * COUT + co_b0 + sco) * CIN) * 4;

  const int lane = tid & 63, wid = tid >> 6;
  const int wm = wid % (PXB / 32), wn = wid / (PXB / 32);
  const int arow = lane & 15, ag = lane >> 4;

  f32x4 acc[2][2];
#pragma unroll
  for (int m = 0; m < 2; ++m)
#pragma unroll
    for (int n = 0; n < 2; ++n) acc[m][n] = (f32x4){0.f, 0.f, 0.f, 0.f};

  float pa[GRP][NKG][8];
  uint_t pu[GRP][NKG][4];
  u32x4 pb[GRP];
  auto loadgrp = [&](int g) {
#pragma unroll
    for (int c = 0; c < GRP; ++c) {
      const int ch = g * GRP + c;
#pragma unroll
      for (int k = 0; k < NKG; ++k) {
        const size_t off = abase + (size_t)(ch * 8 + (kg0 + k * KGSTEP) * 2) * INSTRIDE;
        if constexpr (INB) {
          const ushort_t* p = (const ushort_t*)in_ + off;
          const ushort_t* q = p + INSTRIDE;
          pu[c][k][0] = pk2(p[0], p[1]);
          pu[c][k][1] = pk2(p[WP], p[WP + 1]);
          pu[c][k][2] = pk2(q[0], q[1]);
          pu[c][k][3] = pk2(q[WP], q[WP + 1]);
        } else {
          const float* p = (const float*)in_ + off;
          const float* q = p + INSTRIDE;
          pa[c][k][0] = p[0]; pa[c][k][1] = p[1]; pa[c][k][2] = p[WP]; pa[c][k][3] = p[WP + 1];
          pa[c][k][4] = q[0]; pa[c][k][5] = q[1]; pa[c][k][6] = q[WP]; pa[c][k][7] = q[WP + 1];
        }
      }
      if (bstage) pb[c] = *(const u32x4*)(wrow + (size_t)ch * 32 + skg * 8);
    }
  };

  loadgrp(0);
  for (int g = 0; g < NGRP; ++g) {
    __syncthreads();
#pragma unroll
    for (int c = 0; c < GRP; ++c) {
#pragma unroll
      for (int k = 0; k < NKG; ++k) {
        u32x4 pk;
        if constexpr (INB) {
          pk[0] = pu[c][k][0]; pk[1] = pu[c][k][1];
          pk[2] = pu[c][k][2]; pk[3] = pu[c][k][3];
        } else {
          pk[0] = (uint_t)f2b(pa[c][k][0]) | ((uint_t)f2b(pa[c][k][1]) << 16);
          pk[1] = (uint_t)f2b(pa[c][k][2]) | ((uint_t)f2b(pa[c][k][3]) << 16);
          pk[2] = (uint_t)f2b(pa[c][k][4]) | ((uint_t)f2b(pa[c][k][5]) << 16);
          pk[3] = (uint_t)f2b(pa[c][k][6]) | ((uint_t)f2b(pa[c][k][7]) << 16);
        }
        *(u32x4*)(&lsA[c][spx * 40 + (kg0 + k * KGSTEP) * 8]) = pk;
      }
      if (bstage) *(u32x4*)(&lsB[c][sco * 40 + skg * 8]) = pb[c];
    }
    if (g + 1 < NGRP) loadgrp(g + 1);
    __syncthreads();
#pragma unroll
    for (int c = 0; c < GRP; ++c) {
      const short8 a0 = *(const short8*)(&lsA[c][(wm * 32 + arow) * 40 + ag * 8]);
      const short8 a1 = *(const short8*)(&lsA[c][(wm * 32 + 16 + arow) * 40 + ag * 8]);
      const short8 b0 = *(const short8*)(&lsB[c][(wn * 32 + arow) * 40 + ag * 8]);
      const short8 b1 = *(const short8*)(&lsB[c][(wn * 32 + 16 + arow) * 40 + ag * 8]);
      acc[0][0] = __builtin_amdgcn_mfma_f32_16x16x32_bf16(a0, b0, acc[0][0], 0, 0, 0);
      acc[0][1] = __builtin_amdgcn_mfma_f32_16x16x32_bf16(a0, b1, acc[0][1], 0, 0, 0);
      acc[1][0] = __builtin_amdgcn_mfma_f32_16x16x32_bf16(a1, b0, acc[1][0], 0, 0, 0);
      acc[1][1] = __builtin_amdgcn_mfma_f32_16x16x32_bf16(a1, b1, acc[1][1], 0, 0, 0);
    }
  }

  if constexpr (!FINAL) {
#pragma unroll
    for (int m = 0; m < 2; ++m)
#pragma unroll
      for (int n = 0; n < 2; ++n) {
        const int col = co_b0 + wn * 32 + n * 16 + arow;
        const float bv = bias[col];
#pragma unroll
        for (int r = 0; r < 4; ++r) {
          const int pxl = pxb0 + wm * 32 + m * 16 + ag * 4 + r;
          const int yy = pxl >> WSHIFT, xx = pxl & (W - 1);
          const size_t oidx = (size_t)(b * COUT + col) * OUTSTRIDE
                            + (size_t)(2 * yy + ey + 1) * WOP + (2 * xx + ex + 1);
          const float v = fmaxf(acc[m][n][r] + bv, 0.0f);
          if constexpr (OUTB) ((ushort_t*)out_)[oidx] = f2b(v);
          else ((float*)out_)[oidx] = v;
        }
      }
  } else {
#pragma unroll
    for (int m = 0; m < 2; ++m)
#pragma unroll
      for (int n = 0; n < 2; ++n) {
        const int col = wn * 32 + n * 16 + arow;
        const float bv = bias[col];
#pragma unroll
        for (int r = 0; r < 4; ++r) {
          const int pxl = wm * 32 + m * 16 + ag * 4 + r;
          pxco[pxl][col] = fmaxf(acc[m][n][r] + bv, 0.0f);
        }
      }
    __syncthreads();
    if (tid < PXB) {
      const int pxg = pxb0 + tid;
      const int yy = pxg >> WSHIFT, xx = pxg & (W - 1);
      const int oy = 2 * yy + ey, ox = 2 * xx + ex;
      float o0 = ob[0], o1 = ob[1], o2 = ob[2];
#pragma unroll
      for (int co = 0; co < 32; ++co) {
        const float v = pxco[tid][co];
        o0 = fmaf(ow[co], v, o0);
        o1 = fmaf(ow[32 + co], v, o1);
        o2 = fmaf(ow[64 + co], v, o2);
      }
      float* outf = (float*)out_;
      outf[((size_t)(b * 3 + 0) * 256 + oy) * 256 + ox] = o0;
      outf[((size_t)(b * 3 + 1) * 256 + oy) * 256 + ox] = o1;
      outf[((size_t)(b * 3 + 2) * 256 + oy) * 256 + ox] = o2;
    }
  }
}

// ---------------- VQ (fp32 exact) ----------------
__global__ __launch_bounds__(256) void k_vq(
    const float* __restrict__ zlat, const float* __restrict__ cbT,
    const float* __restrict__ cnorm, const float* __restrict__ cb,
    float* __restrict__ q, float* __restrict__ counts, float* __restrict__ sumsq) {
  const int tid = threadIdx.x;
  const int px0 = blockIdx.x << 4;
  const int b   = px0 >> 10;
  const int pl0 = px0 & 1023;
  __shared__ float zT[64][17];
  __shared__ float rd[16][256];
  __shared__ int   ri[16][256];
  for (int j = tid; j < 1024; j += 256) {
    const int ci = j >> 4, p = j & 15;
    zT[ci][p] = zlat[(size_t)(b * 64 + ci) * 1024 + pl0 + p];
  }
  __syncthreads();
  float dot[4][16];
#pragma unroll
  for (int k = 0; k < 4; ++k)
#pragma unroll
    for (int p = 0; p < 16; ++p) dot[k][p] = 0.0f;
  for (int ci = 0; ci < 64; ++ci) {
    float z[16];
#pragma unroll
    for (int p = 0; p < 16; ++p) z[p] = zT[ci][p];
#pragma unroll
    for (int k = 0; k < 4; ++k) {
      const float cv = cbT[(size_t)ci * 1024 + (k << 8) + tid];
#pragma unroll
      for (int p = 0; p < 16; ++p) dot[k][p] = fmaf(cv, z[p], dot[k][p]);
    }
  }
  float bd[16]; int bi[16];
#pragma unroll
  for (int p = 0; p < 16; ++p) { bd[p] = 3.4e38f; bi[p] = 0; }
#pragma unroll
  for (int k = 0; k < 4; ++k) {
    const int c = (k << 8) + tid;
    const float cn = cnorm[c];
#pragma unroll
    for (int p = 0; p < 16; ++p) {
      const float d = cn - 2.0f * dot[k][p];
      if (d < bd[p]) { bd[p] = d; bi[p] = c; }
    }
  }
#pragma unroll
  for (int p = 0; p < 16; ++p) { rd[p][tid] = bd[p]; ri[p][tid] = bi[p]; }
  __syncthreads();
  for (int s = 128; s >= 1; s >>= 1) {
    if (tid < s) {
#pragma unroll
      for (int p = 0; p < 16; ++p) {
        const float d2 = rd[p][tid + s]; const int i2 = ri[p][tid + s];
        const float d1 = rd[p][tid];     const int i1 = ri[p][tid];
        if (d2 < d1 || (d2 == d1 && i2 < i1)) { rd[p][tid] = d2; ri[p][tid] = i2; }
      }
    }
    __syncthreads();
  }
  if (tid < 16) atomicAdd(&counts[ri[tid][0]], 1.0f);
  const int p    = tid >> 4;
  const int best = ri[p][0];
  const int cb0  = (tid & 15) << 2;
  float ss = 0.0f;
  float* qp = q + (size_t)b * 65536 + pl0 + p;
#pragma unroll
  for (int cc = 0; cc < 4; ++cc) {
    const int ci = cb0 + cc;
    const float qv = cb[(size_t)best * 64 + ci];
    const float zv = zT[ci][p];
    const float df = qv - zv;
    ss += df * df;
    qp[(size_t)ci * 1024] = qv;
  }
#pragma unroll
  for (int o = 32; o > 0; o >>= 1) ss += __shfl_down(ss, o);
  if ((tid & 63) == 0) atomicAdd(sumsq, ss);
}

__global__ void k_final(const float* __restrict__ counts, const float* __restrict__ sumsq,
                        float* __restrict__ out2) {
  const int tid = threadIdx.x;
  float h = 0.0f;
  for (int k = tid; k < 1024; k += 256) {
    const float pr = counts[k] * (1.0f / 32768.0f);
    h -= pr * logf(pr + 1e-10f);
  }
#pragma unroll
  for (int o = 32; o > 0; o >>= 1) h += __shfl_down(h, o);
  __shared__ float hs[4];
  if ((tid & 63) == 0) hs[tid >> 6] = h;
  __syncthreads();
  if (tid == 0) {
    out2[0] = 1.25f * sumsq[0] * (1.0f / 2097152.0f);
    out2[1] = expf(hs[0] + hs[1] + hs[2] + hs[3]);
  }
}

// ---------------- launcher ----------------
extern "C" void kernel_launch(void* const* d_in, const int* in_sizes, int n_in,
                              void* d_out, int out_size, void* d_ws, size_t ws_size,
                              hipStream_t stream) {
  const float* x        = (const float*)d_in[0];
  const float* enc_w0   = (const float*)d_in[1];
  const float* enc_b0   = (const float*)d_in[2];
  const float* enc_w1   = (const float*)d_in[3];
  const float* enc_b1   = (const float*)d_in[4];
  const float* enc_w2   = (const float*)d_in[5];
  const float* enc_b2   = (const float*)d_in[6];
  const float* er0w1    = (const float*)d_in[7];
  const float* er0b1    = (const float*)d_in[8];
  const float* er0w2    = (const float*)d_in[9];
  const float* er0b2    = (const float*)d_in[10];
  const float* er1w1    = (const float*)d_in[11];
  const float* er1b1    = (const float*)d_in[12];
  const float* er1w2    = (const float*)d_in[13];
  const float* er1b2    = (const float*)d_in[14];
  const float* eadj_w   = (const float*)d_in[15];
  const float* eadj_b   = (const float*)d_in[16];
  const float* codebook = (const float*)d_in[17];
  const float* dadj_w   = (const float*)d_in[18];
  const float* dadj_b   = (const float*)d_in[19];
  const float* dr0w1    = (const float*)d_in[20];
  const float* dr0b1    = (const float*)d_in[21];
  const float* dr0w2    = (const float*)d_in[22];
  const float* dr0b2    = (const float*)d_in[23];
  const float* dr1w1    = (const float*)d_in[24];
  const float* dr1b1    = (const float*)d_in[25];
  const float* dr1w2    = (const float*)d_in[26];
  const float* dr1b2    = (const float*)d_in[27];
  const float* tw0      = (const float*)d_in[28];
  const float* tb0      = (const float*)d_in[29];
  const float* tw1      = (const float*)d_in[30];
  const float* tb1      = (const float*)d_in[31];
  const float* tw2      = (const float*)d_in[32];
  const float* tb2      = (const float*)d_in[33];
  const float* out_w    = (const float*)d_in[34];
  const float* out_b    = (const float*)d_in[35];

  float* ws = (float*)d_ws;
  float* A      = ws + A_OFF;
  float* Bb     = ws + B_OFF;
  float* C      = ws + C_OFF;
  float* Dq     = ws + D_OFF;
  float* E      = ws + E_OFF;
  float* Q      = ws + Q_OFF;
  float* cbT    = ws + CBT_OFF;
  float* cnorm  = ws + CNORM_OFF;
  float* counts = ws + COUNTS_OFF;
  float* sumsq  = ws + SUMSQ_OFF;
  ushort_t* Cb16  = (ushort_t*)ws;            // decoder res#2 out (32*256*1156 u16)
  ushort_t* Bb16u = (ushort_t*)(ws + B_OFF);  // tconv0 out (32*128*4356 u16)
  ushort_t* A16u  = (ushort_t*)ws;            // tconv1 out (32*64*16900 u16)

  size_t o = WT_OFF;
  float* wt_enc0  = ws + o; o += (size_t)3 * 16 * 64;
  float* wt_eadj  = ws + o; o += (size_t)256 * 64;
  float* wt_dadj  = ws + o; o += (size_t)64 * 256;
  ushort_t* wbT0 = (ushort_t*)(ws + o); o += 262144;
  ushort_t* wbT1 = (ushort_t*)(ws + o); o += 65536;
  ushort_t* wbT2 = (ushort_t*)(ws + o); o += 16384;
  ushort_t* wsh1 = (ushort_t*)(ws + o); o += 65536;
  ushort_t* wsl1 = (ushort_t*)(ws + o); o += 65536;
  ushort_t* wsh2 = (ushort_t*)(ws + o); o += 262144;
  ushort_t* wsl2 = (ushort_t*)(ws + o); o += 262144;
  ushort_t* w3h_er0 = (ushort_t*)(ws + o); o += 73728;
  ushort_t* w3l_er0 = (ushort_t*)(ws + o); o += 73728;
  ushort_t* w3h_er1 = (ushort_t*)(ws + o); o += 73728;
  ushort_t* w3l_er1 = (ushort_t*)(ws + o); o += 73728;
  ushort_t* w3h_dr0 = (ushort_t*)(ws + o); o += 73728;
  ushort_t* w3l_dr0 = (ushort_t*)(ws + o); o += 73728;
  ushort_t* w3h_dr1 = (ushort_t*)(ws + o); o += 73728;
  ushort_t* w3l_dr1 = (ushort_t*)(ws + o); o += 73728;
  ushort_t* w2h_er0 = (ushort_t*)(ws + o); o += 8192;
  ushort_t* w2l_er0 = (ushort_t*)(ws + o); o += 8192;
  ushort_t* w2h_er1 = (ushort_t*)(ws + o); o += 8192;
  ushort_t* w2l_er1 = (ushort_t*)(ws + o); o += 8192;
  ushort_t* w2h_dr0 = (ushort_t*)(ws + o); o += 8192;
  ushort_t* w2l_dr0 = (ushort_t*)(ws + o); o += 8192;
  ushort_t* w2h_dr1 = (ushort_t*)(ws + o); o += 8192;
  ushort_t* w2l_dr1 = (ushort_t*)(ws + o); o += 8192;

  float* fout = (float*)d_out;

  // targeted zeroing: counters + fp32 halos of A, Bb (encoder phase)
  k_zero<<<4, 256, 0, stream>>>(counts, sumsq);
  k_halo<<<2048, 64, 0, stream>>>(A, 130, 130);
  k_halo<<<4096, 64, 0, stream>>>(Bb, 66, 66);

  // consolidated weight prep
  k_wt_conv_multi<<<dim3(64, 3), 256, 0, stream>>>(enc_w0, wt_enc0, eadj_w, wt_eadj,
                                                   dadj_w, wt_dadj);
  k_wtb_multi<<<dim3(2048, 3), 256, 0, stream>>>(tw0, wbT0, tw1, wbT1, tw2, wbT2);
  k_wsplit_enc<<<dim3(2048, 2), 256, 0, stream>>>(enc_w1, wsh1, wsl1, enc_w2, wsh2, wsl2);
  k_wsplit_w2m<<<dim3(64, 4), 256, 0, stream>>>(er0w2, w2h_er0, w2l_er0,
                                                er1w2, w2h_er1, w2l_er1,
                                                dr0w2, w2h_dr0, w2l_dr0,
                                                dr1w2, w2h_dr1, w2l_dr1);
  k_wt3split_multi<<<dim3(576, 4), 256, 0, stream>>>(er0w1, w3h_er0, w3l_er0,
                                                     er1w1, w3h_er1, w3l_er1,
                                                     dr0w1, w3h_dr0, w3l_dr0,
                                                     dr1w1, w3h_dr1, w3l_dr1);
  k_cbt<<<4, 256, 0, stream>>>(codebook, cbT, cnorm);

  // ---------- encoder (split-bf16 MFMA ~ fp32 accuracy; protects VQ argmin) ----------
  k_conv4s2_s3<<<dim3(16, 4, 32), 256, 0, stream>>>(x, wt_enc0, enc_b0, A);
  k_conv4s2_mfma<6, 64, 128, 130, 16900, 66, 4356>
      <<<dim3(64, 2, 32), 256, 0, stream>>>(A, wsh1, wsl1, enc_b1, Bb);
  // A now dead -> zero C/Dq halos
  k_halo<<<8192, 64, 0, stream>>>(C, 34, 34);
  k_halo<<<8192, 64, 0, stream>>>(Dq, 34, 34);
  k_conv4s2_mfma<5, 128, 256, 66, 4356, 34, 1156>
      <<<dim3(16, 4, 32), 256, 0, stream>>>(Bb, wsh2, wsl2, enc_b2, C);
  // Bb fp32 now dead -> zero Bb16 u16 halos (for decoder tconv0 output)
  k_halo_h<<<4096, 64, 0, stream>>>(Bb16u, 66, 66);
  k_res_mfma<0><<<dim3(16, 1, 32), 512, 0, stream>>>(C, w3h_er0, w3l_er0, er0b1,
                                                     w2h_er0, w2l_er0, er0b2, Dq);
  k_res_mfma<0><<<dim3(16, 1, 32), 512, 0, stream>>>(Dq, w3h_er1, w3l_er1, er1b1,
                                                     w2h_er1, w2l_er1, er1b2, C);
  k_conv1x1_px<0, 0, 1, 0><<<dim3(4, 4, 32), 256, 0, stream>>>(C, wt_eadj, eadj_b, nullptr, E, 256, 64);
  // ---------- VQ (fp32 exact) ----------
  k_vq<<<2048, 256, 0, stream>>>(E, cbT, cnorm, codebook, Q, counts, sumsq);
  // ---------- decoder ----------
  k_conv1x1_px<0, 0, 0, 1><<<dim3(4, 16, 32), 256, 0, stream>>>(Q, wt_dadj, dadj_b, nullptr, C, 64, 256);
  k_res_mfma<0><<<dim3(16, 1, 32), 512, 0, stream>>>(C, w3h_dr0, w3l_dr0, dr0b1,
                                                     w2h_dr0, w2l_dr0, dr0b2, Dq);
  // C fp32 dead (res#1 consumed it) -> zero Cb16 u16 halos, then res#2 writes bf16 interior
  k_halo_h<<<8192, 64, 0, stream>>>(Cb16, 34, 34);
  k_res_mfma<1><<<dim3(16, 1, 32), 512, 0, stream>>>(Dq, w3h_dr1, w3l_dr1, dr1b1,
                                                     w2h_dr1, w2l_dr1, dr1b2, (float*)Cb16);
  // bf16 MFMA transposed convs (bf16 activation planes end-to-end)
  k_tconv_mfma<64, 64, 5, 256, 128, 34, 1156, 66, 4356, 0, 2, 1, 1>
      <<<dim3(16, 8, 32), 256, 0, stream>>>(Cb16, wbT0, tb0, nullptr, nullptr, Bb16u);
  // Cb16/Dq/E/Q dead -> zero A16 u16 halos
  k_halo_h<<<2048, 64, 0, stream>>>(A16u, 130, 130);
  k_tconv_mfma<64, 64, 6, 128, 64, 66, 4356, 130, 16900, 0, 2, 1, 1>
      <<<dim3(64, 4, 32), 256, 0, stream>>>(Bb16u, wbT1, tb1, nullptr, nullptr, A16u);
  k_tconv_mfma<128, 32, 7, 64, 32, 130, 16900, 0, 0, 1, 1, 1, 0>
      <<<dim3(128, 4, 32), 256, 0, stream>>>(A16u, wbT2, tb2, out_w, out_b, fout);
  k_final<<<1, 256, 0, stream>>>(counts, sumsq, fout + 6291456);
}